// Round 1
// baseline (13370.251 us; speedup 1.0000x reference)
//
#include <hip/hip_runtime.h>

#define NFEAT_IN 256
#define HDIM 64
#define DLAT 16
#define NC 8
#define NL 10
#define KPROP 10

__device__ __forceinline__ float softplusf(float x) {
    return (x > 20.f) ? x : log1pf(expf(x));
}

// GEMM1: t1t[j][i] = (x @ W1 + b1)[i][j]  (stored transposed for coalescing)
__global__ __launch_bounds__(256) void k_gemm1(
        const float* __restrict__ x, const float* __restrict__ W1,
        const float* __restrict__ b1, float* __restrict__ t1t, int n) {
    int row = blockIdx.x * 256 + threadIdx.x;
    if (row >= n) return;
    float acc[HDIM];
    #pragma unroll
    for (int j = 0; j < HDIM; ++j) acc[j] = b1[j];
    const float4* x4 = reinterpret_cast<const float4*>(x + (size_t)row * NFEAT_IN);
    for (int k4 = 0; k4 < NFEAT_IN / 4; ++k4) {
        float4 xv = x4[k4];
        const float* w = W1 + k4 * 4 * HDIM;   // thread-uniform -> scalar loads
        #pragma unroll
        for (int j = 0; j < HDIM; ++j) {
            acc[j] += xv.x * w[j] + xv.y * w[HDIM + j]
                    + xv.z * w[2 * HDIM + j] + xv.w * w[3 * HDIM + j];
        }
    }
    #pragma unroll
    for (int j = 0; j < HDIM; ++j) t1t[(size_t)j * n + row] = acc[j];
}

// per-feature sum & sumsq over transposed activations [64][n]
__global__ __launch_bounds__(256) void k_stats(
        const float* __restrict__ tt, float* __restrict__ sum,
        float* __restrict__ sq, int n) {
    int feat = blockIdx.x >> 3;
    int chunk = blockIdx.x & 7;
    const float4* p = reinterpret_cast<const float4*>(tt + (size_t)feat * n);
    int n4 = n / 4;
    float s = 0.f, q = 0.f;
    for (int i = chunk * 256 + threadIdx.x; i < n4; i += 8 * 256) {
        float4 v = p[i];
        s += v.x + v.y + v.z + v.w;
        q += v.x * v.x + v.y * v.y + v.z * v.z + v.w * v.w;
    }
    if (chunk == 0 && threadIdx.x < (n & 3)) {
        float v = tt[(size_t)feat * n + (n & ~3) + threadIdx.x];
        s += v; q += v * v;
    }
    #pragma unroll
    for (int off = 32; off; off >>= 1) {
        s += __shfl_down(s, off, 64);
        q += __shfl_down(q, off, 64);
    }
    __shared__ float ls[4], lq[4];
    int wid = threadIdx.x >> 6, lane = threadIdx.x & 63;
    if (lane == 0) { ls[wid] = s; lq[wid] = q; }
    __syncthreads();
    if (threadIdx.x == 0) {
        atomicAdd(&sum[feat], ls[0] + ls[1] + ls[2] + ls[3]);
        atomicAdd(&sq[feat],  lq[0] + lq[1] + lq[2] + lq[3]);
    }
}

// fold BN into per-feature affine: y = A*x + B
__global__ void k_finalize(const float* __restrict__ sum, const float* __restrict__ sq,
        const float* __restrict__ g, const float* __restrict__ be,
        float* __restrict__ A, float* __restrict__ B, int n) {
    int j = threadIdx.x;
    if (j >= HDIM) return;
    float mean = sum[j] / (float)n;
    float var = sq[j] / (float)n - mean * mean;
    float istd = 1.0f / sqrtf(var + 1e-5f);
    A[j] = g[j] * istd;
    B[j] = be[j] - mean * istd * g[j];
}

// GEMM2: t2t[j][i] = (relu(bn1(t1)) @ W2 + b2)[i][j]
__global__ __launch_bounds__(256) void k_gemm2(
        const float* __restrict__ t1t, const float* __restrict__ A1,
        const float* __restrict__ B1, const float* __restrict__ W2,
        const float* __restrict__ b2, float* __restrict__ t2t, int n) {
    int row = blockIdx.x * 256 + threadIdx.x;
    if (row >= n) return;
    float acc[HDIM];
    #pragma unroll
    for (int j = 0; j < HDIM; ++j) acc[j] = b2[j];
    for (int k = 0; k < HDIM; ++k) {
        float hv = fmaxf(A1[k] * t1t[(size_t)k * n + row] + B1[k], 0.f);
        const float* w = W2 + k * HDIM;
        #pragma unroll
        for (int j = 0; j < HDIM; ++j) acc[j] += hv * w[j];
    }
    #pragma unroll
    for (int j = 0; j < HDIM; ++j) t2t[(size_t)j * n + row] = acc[j];
}

// z = relu(bn2(t2)) @ W3 + b3 ; radial-flow log prob ; beta_ft
__global__ __launch_bounds__(256) void k_zflow(
        const float* __restrict__ t2t, const float* __restrict__ A2,
        const float* __restrict__ B2, const float* __restrict__ W3,
        const float* __restrict__ b3, const float* __restrict__ x0,
        const float* __restrict__ ap, const float* __restrict__ bp,
        const float* __restrict__ mu, const float* __restrict__ lv,
        float* __restrict__ out_z, float* __restrict__ out_logq,
        float* __restrict__ out_beta, int n) {
    __shared__ float a_s[NL * NC], b_s[NL * NC], x0_s[NL * NC * DLAT];
    __shared__ float mu_s[NC * DLAT], iv_s[NC * DLAT], slv_s[NC];
    for (int i = threadIdx.x; i < NL * NC; i += 256) {
        float a = softplusf(ap[i]);
        a_s[i] = a;
        b_s[i] = softplusf(bp[i]) - a;
    }
    for (int i = threadIdx.x; i < NL * NC * DLAT; i += 256) x0_s[i] = x0[i];
    for (int i = threadIdx.x; i < NC * DLAT; i += 256) {
        mu_s[i] = mu[i];
        iv_s[i] = expf(-lv[i]);
    }
    if (threadIdx.x < NC) {
        float s = 0.f;
        for (int d = 0; d < DLAT; ++d) s += lv[threadIdx.x * DLAT + d];
        slv_s[threadIdx.x] = s;
    }
    __syncthreads();
    int row = blockIdx.x * 256 + threadIdx.x;
    if (row >= n) return;
    float z[DLAT];
    #pragma unroll
    for (int j = 0; j < DLAT; ++j) z[j] = b3[j];
    for (int k = 0; k < HDIM; ++k) {
        float hv = fmaxf(A2[k] * t2t[(size_t)k * n + row] + B2[k], 0.f);
        const float* w = W3 + k * DLAT;
        #pragma unroll
        for (int j = 0; j < DLAT; ++j) z[j] += hv * w[j];
    }
    #pragma unroll
    for (int j = 0; j < DLAT; ++j) out_z[(size_t)row * DLAT + j] = z[j];

    for (int c = 0; c < NC; ++c) {
        float zz[DLAT];
        #pragma unroll
        for (int d = 0; d < DLAT; ++d) zz[d] = z[d];
        float log_det = 0.f;
        for (int l = NL - 1; l >= 0; --l) {
            float a = a_s[l * NC + c], b = b_s[l * NC + c];
            const float* x0p = &x0_s[(l * NC + c) * DLAT];
            float diff[DLAT];
            float r2 = 0.f;
            #pragma unroll
            for (int d = 0; d < DLAT; ++d) {
                diff[d] = zz[d] - x0p[d];
                r2 += diff[d] * diff[d];
            }
            float r = fmaxf(sqrtf(r2), 1e-8f);
            float h = 1.f / (a + r);
            float bh = b * h;
            #pragma unroll
            for (int d = 0; d < DLAT; ++d) zz[d] += bh * diff[d];
            log_det += (DLAT - 1) * log1pf(bh) + log1pf(bh - bh * h * r);
        }
        float quad = 0.f;
        #pragma unroll
        for (int d = 0; d < DLAT; ++d) {
            float dd = zz[d] - mu_s[c * DLAT + d];
            quad += dd * dd * iv_s[c * DLAT + d];
        }
        float lq = -14.70301653f - 0.5f * slv_s[c] - 0.5f * quad + log_det;
        out_logq[(size_t)row * NC + c] = lq;
        float w = fminf(fmaxf(lq + 20.24819398f, -30.f), 30.f);
        out_beta[(size_t)row * NC + c] = expf(w);
    }
}

__global__ void k_deg(const int* __restrict__ rows, float* __restrict__ deg,
                      int e, int n) {
    int stride = gridDim.x * blockDim.x;
    for (int i = blockIdx.x * blockDim.x + threadIdx.x; i < e; i += stride) {
        int r = rows[i];
        if ((unsigned)r < (unsigned)n) atomicAdd(&deg[r], 1.0f);
    }
}

__global__ void k_dis(const float* __restrict__ deg, float* __restrict__ dis, int n) {
    int i = blockIdx.x * blockDim.x + threadIdx.x;
    if (i < n) dis[i] = 1.0f / sqrtf(deg[i] + 1.0f);   // +1 = self loop
}

// msg[i] = dis[i]^2 * h[i]   (self-loop contribution, also zero-initializes msg)
__global__ void k_initmsg(const float* __restrict__ h, const float* __restrict__ dis,
        float* __restrict__ msg, int n) {
    int i = blockIdx.x * blockDim.x + threadIdx.x;
    if (i >= n) return;
    float s = dis[i] * dis[i];
    const float4* hp = reinterpret_cast<const float4*>(h + (size_t)i * NC);
    float4* mp = reinterpret_cast<float4*>(msg + (size_t)i * NC);
    float4 h0 = hp[0], h1 = hp[1];
    mp[0] = make_float4(s * h0.x, s * h0.y, s * h0.z, s * h0.w);
    mp[1] = make_float4(s * h1.x, s * h1.y, s * h1.z, s * h1.w);
}

__global__ __launch_bounds__(256) void k_scatter(const int* __restrict__ rows,
        const int* __restrict__ cols, const float* __restrict__ dis,
        const float* __restrict__ h, float* __restrict__ msg, int e, int n) {
    int stride = gridDim.x * blockDim.x;
    for (int i = blockIdx.x * blockDim.x + threadIdx.x; i < e; i += stride) {
        int r = rows[i], cl = cols[i];
        if ((unsigned)r >= (unsigned)n || (unsigned)cl >= (unsigned)n) continue;
        float w = dis[r] * dis[cl];
        const float4* hp = reinterpret_cast<const float4*>(h + (size_t)cl * NC);
        float4 h0 = hp[0], h1 = hp[1];
        float* m = msg + (size_t)r * NC;
        atomicAdd(m + 0, w * h0.x); atomicAdd(m + 1, w * h0.y);
        atomicAdd(m + 2, w * h0.z); atomicAdd(m + 3, w * h0.w);
        atomicAdd(m + 4, w * h1.x); atomicAdd(m + 5, w * h1.y);
        atomicAdd(m + 6, w * h1.z); atomicAdd(m + 7, w * h1.w);
    }
}

__global__ void k_update(const float* __restrict__ msg, const float* __restrict__ beta,
        float* __restrict__ h, int n8_4) {
    int i = blockIdx.x * blockDim.x + threadIdx.x;
    if (i >= n8_4) return;
    const float4* m = reinterpret_cast<const float4*>(msg);
    const float4* b = reinterpret_cast<const float4*>(beta);
    float4* hp = reinterpret_cast<float4*>(h);
    float4 mv = m[i], bv = b[i];
    hp[i] = make_float4(0.9f * mv.x + 0.1f * bv.x, 0.9f * mv.y + 0.1f * bv.y,
                        0.9f * mv.z + 0.1f * bv.z, 0.9f * mv.w + 0.1f * bv.w);
}

__global__ void k_final(const float* __restrict__ h, float* __restrict__ out_alpha,
        float* __restrict__ out_probs, int n) {
    int i = blockIdx.x * blockDim.x + threadIdx.x;
    if (i >= n) return;
    float a[NC];
    float s = 0.f;
    #pragma unroll
    for (int c = 0; c < NC; ++c) {
        float v = h[(size_t)i * NC + c];
        v = 0.001f + fmaxf(v, 0.f);
        a[c] = v; s += v;
    }
    float inv = 1.f / s;
    #pragma unroll
    for (int c = 0; c < NC; ++c) {
        out_alpha[(size_t)i * NC + c] = a[c];
        out_probs[(size_t)i * NC + c] = a[c] * inv;
    }
}

extern "C" void kernel_launch(void* const* d_in, const int* in_sizes, int n_in,
                              void* d_out, int out_size, void* d_ws, size_t ws_size,
                              hipStream_t stream) {
    const float* x   = (const float*)d_in[0];
    const int*   ei  = (const int*)d_in[1];
    const float* W1  = (const float*)d_in[2];
    const float* b1  = (const float*)d_in[3];
    const float* g1  = (const float*)d_in[4];
    const float* be1 = (const float*)d_in[5];
    const float* W2  = (const float*)d_in[6];
    const float* b2  = (const float*)d_in[7];
    const float* g2  = (const float*)d_in[8];
    const float* be2 = (const float*)d_in[9];
    const float* W3  = (const float*)d_in[10];
    const float* b3  = (const float*)d_in[11];
    const float* x0  = (const float*)d_in[12];
    const float* ap  = (const float*)d_in[13];
    const float* bp  = (const float*)d_in[14];
    const float* mu  = (const float*)d_in[15];
    const float* lv  = (const float*)d_in[16];

    int n = in_sizes[0] / NFEAT_IN;   // 100000
    int e = in_sizes[1] / 2;          // 3200000
    const int* rows = ei;
    const int* cols = ei + e;

    float* ws = (float*)d_ws;
    float* t1t = ws;                               // 64*n
    float* t2t = t1t + (size_t)HDIM * n;           // 64*n
    float* h   = t2t + (size_t)HDIM * n;           // 8*n
    float* msg = h   + (size_t)NC * n;             // 8*n
    float* deg = msg + (size_t)NC * n;             // n
    float* dis = deg + n;                          // n
    float* stats = dis + n;                        // 512
    float *sum1 = stats,       *sq1 = stats + 64,  *A1 = stats + 128, *B1 = stats + 192;
    float *sum2 = stats + 256, *sq2 = stats + 320, *A2 = stats + 384, *B2 = stats + 448;

    float* out = (float*)d_out;
    float* out_alpha = out;
    float* out_probs = out + (size_t)n * NC;
    float* out_z     = out + (size_t)2 * n * NC;
    float* out_beta  = out_z + (size_t)n * DLAT;
    float* out_logq  = out_beta + (size_t)n * NC;

    hipMemsetAsync(stats, 0, 512 * sizeof(float), stream);
    hipMemsetAsync(deg, 0, (size_t)n * sizeof(float), stream);

    int nb = (n + 255) / 256;
    k_gemm1<<<nb, 256, 0, stream>>>(x, W1, b1, t1t, n);
    k_stats<<<HDIM * 8, 256, 0, stream>>>(t1t, sum1, sq1, n);
    k_finalize<<<1, 64, 0, stream>>>(sum1, sq1, g1, be1, A1, B1, n);
    k_gemm2<<<nb, 256, 0, stream>>>(t1t, A1, B1, W2, b2, t2t, n);
    k_stats<<<HDIM * 8, 256, 0, stream>>>(t2t, sum2, sq2, n);
    k_finalize<<<1, 64, 0, stream>>>(sum2, sq2, g2, be2, A2, B2, n);
    k_zflow<<<nb, 256, 0, stream>>>(t2t, A2, B2, W3, b3, x0, ap, bp, mu, lv,
                                    out_z, out_logq, out_beta, n);
    k_deg<<<1024, 256, 0, stream>>>(rows, deg, e, n);
    k_dis<<<nb, 256, 0, stream>>>(deg, dis, n);
    for (int it = 0; it < KPROP; ++it) {
        const float* hin = (it == 0) ? out_beta : h;
        k_initmsg<<<nb, 256, 0, stream>>>(hin, dis, msg, n);
        k_scatter<<<2048, 256, 0, stream>>>(rows, cols, dis, hin, msg, e, n);
        k_update<<<(n * NC / 4 + 255) / 256, 256, 0, stream>>>(msg, out_beta, h, n * NC / 4);
    }
    k_final<<<nb, 256, 0, stream>>>(h, out_alpha, out_probs, n);
}

// Round 2
// 1269.339 us; speedup vs baseline: 10.5332x; 10.5332x over previous
//
#include <hip/hip_runtime.h>

#define NFEAT_IN 256
#define HDIM 64
#define DLAT 16
#define NC 8
#define NL 10
#define KPROP 10

__device__ __forceinline__ float softplusf(float x) {
    return (x > 20.f) ? x : log1pf(expf(x));
}

// ---------------- encoder (unchanged from round 0) ----------------

__global__ __launch_bounds__(256) void k_gemm1(
        const float* __restrict__ x, const float* __restrict__ W1,
        const float* __restrict__ b1, float* __restrict__ t1t, int n) {
    int row = blockIdx.x * 256 + threadIdx.x;
    if (row >= n) return;
    float acc[HDIM];
    #pragma unroll
    for (int j = 0; j < HDIM; ++j) acc[j] = b1[j];
    const float4* x4 = reinterpret_cast<const float4*>(x + (size_t)row * NFEAT_IN);
    for (int k4 = 0; k4 < NFEAT_IN / 4; ++k4) {
        float4 xv = x4[k4];
        const float* w = W1 + k4 * 4 * HDIM;
        #pragma unroll
        for (int j = 0; j < HDIM; ++j) {
            acc[j] += xv.x * w[j] + xv.y * w[HDIM + j]
                    + xv.z * w[2 * HDIM + j] + xv.w * w[3 * HDIM + j];
        }
    }
    #pragma unroll
    for (int j = 0; j < HDIM; ++j) t1t[(size_t)j * n + row] = acc[j];
}

__global__ __launch_bounds__(256) void k_stats(
        const float* __restrict__ tt, float* __restrict__ sum,
        float* __restrict__ sq, int n) {
    int feat = blockIdx.x >> 3;
    int chunk = blockIdx.x & 7;
    const float4* p = reinterpret_cast<const float4*>(tt + (size_t)feat * n);
    int n4 = n / 4;
    float s = 0.f, q = 0.f;
    for (int i = chunk * 256 + threadIdx.x; i < n4; i += 8 * 256) {
        float4 v = p[i];
        s += v.x + v.y + v.z + v.w;
        q += v.x * v.x + v.y * v.y + v.z * v.z + v.w * v.w;
    }
    if (chunk == 0 && threadIdx.x < (n & 3)) {
        float v = tt[(size_t)feat * n + (n & ~3) + threadIdx.x];
        s += v; q += v * v;
    }
    #pragma unroll
    for (int off = 32; off; off >>= 1) {
        s += __shfl_down(s, off, 64);
        q += __shfl_down(q, off, 64);
    }
    __shared__ float ls[4], lq[4];
    int wid = threadIdx.x >> 6, lane = threadIdx.x & 63;
    if (lane == 0) { ls[wid] = s; lq[wid] = q; }
    __syncthreads();
    if (threadIdx.x == 0) {
        atomicAdd(&sum[feat], ls[0] + ls[1] + ls[2] + ls[3]);
        atomicAdd(&sq[feat],  lq[0] + lq[1] + lq[2] + lq[3]);
    }
}

__global__ void k_finalize(const float* __restrict__ sum, const float* __restrict__ sq,
        const float* __restrict__ g, const float* __restrict__ be,
        float* __restrict__ A, float* __restrict__ B, int n) {
    int j = threadIdx.x;
    if (j >= HDIM) return;
    float mean = sum[j] / (float)n;
    float var = sq[j] / (float)n - mean * mean;
    float istd = 1.0f / sqrtf(var + 1e-5f);
    A[j] = g[j] * istd;
    B[j] = be[j] - mean * istd * g[j];
}

__global__ __launch_bounds__(256) void k_gemm2(
        const float* __restrict__ t1t, const float* __restrict__ A1,
        const float* __restrict__ B1, const float* __restrict__ W2,
        const float* __restrict__ b2, float* __restrict__ t2t, int n) {
    int row = blockIdx.x * 256 + threadIdx.x;
    if (row >= n) return;
    float acc[HDIM];
    #pragma unroll
    for (int j = 0; j < HDIM; ++j) acc[j] = b2[j];
    for (int k = 0; k < HDIM; ++k) {
        float hv = fmaxf(A1[k] * t1t[(size_t)k * n + row] + B1[k], 0.f);
        const float* w = W2 + k * HDIM;
        #pragma unroll
        for (int j = 0; j < HDIM; ++j) acc[j] += hv * w[j];
    }
    #pragma unroll
    for (int j = 0; j < HDIM; ++j) t2t[(size_t)j * n + row] = acc[j];
}

__global__ __launch_bounds__(256) void k_zflow(
        const float* __restrict__ t2t, const float* __restrict__ A2,
        const float* __restrict__ B2, const float* __restrict__ W3,
        const float* __restrict__ b3, const float* __restrict__ x0,
        const float* __restrict__ ap, const float* __restrict__ bp,
        const float* __restrict__ mu, const float* __restrict__ lv,
        float* __restrict__ out_z, float* __restrict__ out_logq,
        float* __restrict__ out_beta, int n) {
    __shared__ float a_s[NL * NC], b_s[NL * NC], x0_s[NL * NC * DLAT];
    __shared__ float mu_s[NC * DLAT], iv_s[NC * DLAT], slv_s[NC];
    for (int i = threadIdx.x; i < NL * NC; i += 256) {
        float a = softplusf(ap[i]);
        a_s[i] = a;
        b_s[i] = softplusf(bp[i]) - a;
    }
    for (int i = threadIdx.x; i < NL * NC * DLAT; i += 256) x0_s[i] = x0[i];
    for (int i = threadIdx.x; i < NC * DLAT; i += 256) {
        mu_s[i] = mu[i];
        iv_s[i] = expf(-lv[i]);
    }
    if (threadIdx.x < NC) {
        float s = 0.f;
        for (int d = 0; d < DLAT; ++d) s += lv[threadIdx.x * DLAT + d];
        slv_s[threadIdx.x] = s;
    }
    __syncthreads();
    int row = blockIdx.x * 256 + threadIdx.x;
    if (row >= n) return;
    float z[DLAT];
    #pragma unroll
    for (int j = 0; j < DLAT; ++j) z[j] = b3[j];
    for (int k = 0; k < HDIM; ++k) {
        float hv = fmaxf(A2[k] * t2t[(size_t)k * n + row] + B2[k], 0.f);
        const float* w = W3 + k * DLAT;
        #pragma unroll
        for (int j = 0; j < DLAT; ++j) z[j] += hv * w[j];
    }
    #pragma unroll
    for (int j = 0; j < DLAT; ++j) out_z[(size_t)row * DLAT + j] = z[j];

    for (int c = 0; c < NC; ++c) {
        float zz[DLAT];
        #pragma unroll
        for (int d = 0; d < DLAT; ++d) zz[d] = z[d];
        float log_det = 0.f;
        for (int l = NL - 1; l >= 0; --l) {
            float a = a_s[l * NC + c], b = b_s[l * NC + c];
            const float* x0p = &x0_s[(l * NC + c) * DLAT];
            float diff[DLAT];
            float r2 = 0.f;
            #pragma unroll
            for (int d = 0; d < DLAT; ++d) {
                diff[d] = zz[d] - x0p[d];
                r2 += diff[d] * diff[d];
            }
            float r = fmaxf(sqrtf(r2), 1e-8f);
            float h = 1.f / (a + r);
            float bh = b * h;
            #pragma unroll
            for (int d = 0; d < DLAT; ++d) zz[d] += bh * diff[d];
            log_det += (DLAT - 1) * log1pf(bh) + log1pf(bh - bh * h * r);
        }
        float quad = 0.f;
        #pragma unroll
        for (int d = 0; d < DLAT; ++d) {
            float dd = zz[d] - mu_s[c * DLAT + d];
            quad += dd * dd * iv_s[c * DLAT + d];
        }
        float lq = -14.70301653f - 0.5f * slv_s[c] - 0.5f * quad + log_det;
        out_logq[(size_t)row * NC + c] = lq;
        float w = fminf(fmaxf(lq + 20.24819398f, -30.f), 30.f);
        out_beta[(size_t)row * NC + c] = expf(w);
    }
}

// ---------------- CSR build (one-time) ----------------

__global__ void k_count(const int* __restrict__ rows, const int* __restrict__ cols,
                        int* __restrict__ cnt, int e, int n) {
    int stride = gridDim.x * blockDim.x;
    for (int i = blockIdx.x * blockDim.x + threadIdx.x; i < e; i += stride) {
        int r = rows[i], c = cols[i];
        if ((unsigned)r < (unsigned)n && (unsigned)c < (unsigned)n)
            atomicAdd(&cnt[r], 1);
    }
}

__global__ void k_dis(const int* __restrict__ cnt, float* __restrict__ dis, int n) {
    int i = blockIdx.x * blockDim.x + threadIdx.x;
    if (i < n) dis[i] = rsqrtf((float)cnt[i] + 1.0f);   // +1 = self loop
}

// block-level partial sums over 1024-element chunks
__global__ __launch_bounds__(256) void k_scan_block(
        const int* __restrict__ cnt, int* __restrict__ bsum, int n) {
    int t = threadIdx.x, b = blockIdx.x;
    int base = b * 1024 + t * 4;
    int s = 0;
    #pragma unroll
    for (int k = 0; k < 4; ++k) { int i = base + k; if (i < n) s += cnt[i]; }
    __shared__ int sh[256];
    sh[t] = s; __syncthreads();
    for (int off = 128; off; off >>= 1) {
        if (t < off) sh[t] += sh[t + off];
        __syncthreads();
    }
    if (t == 0) bsum[b] = sh[0];
}

__global__ void k_scan_top(int* __restrict__ bsum, int* __restrict__ boff,
                           int nb, int* __restrict__ rp, int n) {
    if (threadIdx.x == 0 && blockIdx.x == 0) {
        int acc = 0;
        for (int b = 0; b < nb; ++b) { boff[b] = acc; acc += bsum[b]; }
        rp[n] = acc;
    }
}

__global__ __launch_bounds__(256) void k_scan_write(
        const int* __restrict__ cnt, const int* __restrict__ boff,
        int* __restrict__ rp, int n) {
    int t = threadIdx.x, b = blockIdx.x;
    int base = b * 1024 + t * 4;
    int v[4]; int s = 0;
    #pragma unroll
    for (int k = 0; k < 4; ++k) { int i = base + k; v[k] = (i < n) ? cnt[i] : 0; s += v[k]; }
    __shared__ int sh[256];
    sh[t] = s; __syncthreads();
    for (int off = 1; off < 256; off <<= 1) {
        int x = (t >= off) ? sh[t - off] : 0;
        __syncthreads();
        sh[t] += x;
        __syncthreads();
    }
    int run = boff[b] + sh[t] - s;   // exclusive prefix for this thread
    #pragma unroll
    for (int k = 0; k < 4; ++k) {
        int i = base + k;
        if (i < n) rp[i] = run;
        run += v[k];
    }
}

__global__ __launch_bounds__(256) void k_place(
        const int* __restrict__ rows, const int* __restrict__ colsrc,
        const float* __restrict__ dis, const int* __restrict__ rp,
        int* __restrict__ cur, int* __restrict__ ecol, float* __restrict__ ew,
        int e, int n) {
    int stride = gridDim.x * blockDim.x;
    for (int i = blockIdx.x * blockDim.x + threadIdx.x; i < e; i += stride) {
        int r = rows[i], c = colsrc[i];
        if ((unsigned)r >= (unsigned)n || (unsigned)c >= (unsigned)n) continue;
        int pos = rp[r] + atomicAdd(&cur[r], 1);
        ecol[pos] = c;
        ew[pos] = dis[r] * dis[c];
    }
}

// ---------------- APPNP gather iteration ----------------
// 8 lanes per row (one per class channel); self-loop + 0.9*msg + 0.1*beta fused.
__global__ __launch_bounds__(256) void k_gather(
        const int* __restrict__ rp, const int* __restrict__ ecol,
        const float* __restrict__ ew, const float* __restrict__ hin,
        const float* __restrict__ beta, const float* __restrict__ dis,
        float* __restrict__ hout, int n) {
    int g = (blockIdx.x * blockDim.x + threadIdx.x) >> 3;
    int c = threadIdx.x & 7;
    int ngroups = (gridDim.x * blockDim.x) >> 3;
    for (int row = g; row < n; row += ngroups) {
        int s = rp[row], epos_end = rp[row + 1];
        float d = dis[row];
        float acc = d * d * hin[(size_t)row * NC + c];   // self loop
        for (int ep = s; ep < epos_end; ++ep) {
            int cl = ecol[ep];
            acc += ew[ep] * hin[(size_t)cl * NC + c];
        }
        hout[(size_t)row * NC + c] = 0.9f * acc + 0.1f * beta[(size_t)row * NC + c];
    }
}

__global__ void k_final(const float* __restrict__ h, float* __restrict__ out_alpha,
        float* __restrict__ out_probs, int n) {
    int i = blockIdx.x * blockDim.x + threadIdx.x;
    if (i >= n) return;
    float a[NC];
    float s = 0.f;
    #pragma unroll
    for (int c = 0; c < NC; ++c) {
        float v = h[(size_t)i * NC + c];
        v = 0.001f + fmaxf(v, 0.f);
        a[c] = v; s += v;
    }
    float inv = 1.f / s;
    #pragma unroll
    for (int c = 0; c < NC; ++c) {
        out_alpha[(size_t)i * NC + c] = a[c];
        out_probs[(size_t)i * NC + c] = a[c] * inv;
    }
}

extern "C" void kernel_launch(void* const* d_in, const int* in_sizes, int n_in,
                              void* d_out, int out_size, void* d_ws, size_t ws_size,
                              hipStream_t stream) {
    const float* x   = (const float*)d_in[0];
    const int*   ei  = (const int*)d_in[1];
    const float* W1  = (const float*)d_in[2];
    const float* b1  = (const float*)d_in[3];
    const float* g1  = (const float*)d_in[4];
    const float* be1 = (const float*)d_in[5];
    const float* W2  = (const float*)d_in[6];
    const float* b2  = (const float*)d_in[7];
    const float* g2  = (const float*)d_in[8];
    const float* be2 = (const float*)d_in[9];
    const float* W3  = (const float*)d_in[10];
    const float* b3  = (const float*)d_in[11];
    const float* x0  = (const float*)d_in[12];
    const float* ap  = (const float*)d_in[13];
    const float* bp  = (const float*)d_in[14];
    const float* mu  = (const float*)d_in[15];
    const float* lv  = (const float*)d_in[16];

    int n = in_sizes[0] / NFEAT_IN;   // 100000
    int e = in_sizes[1] / 2;          // 3200000
    const int* rows = ei;
    const int* cols = ei + e;

    float* ws = (float*)d_ws;
    float* t1t = ws;                               // 64*n floats
    float* t2t = t1t + (size_t)HDIM * n;           // 64*n floats
    float* h0  = t2t + (size_t)HDIM * n;           // 8*n
    float* h1  = h0  + (size_t)NC * n;             // 8*n
    float* dis = h1  + (size_t)NC * n;             // n
    float* stats = dis + n;                        // 512
    float *sum1 = stats,       *sq1 = stats + 64,  *A1 = stats + 128, *B1 = stats + 192;
    float *sum2 = stats + 256, *sq2 = stats + 320, *A2 = stats + 384, *B2 = stats + 448;

    // CSR overlays: t1t/t2t are dead after k_zflow.
    int*   ecol = (int*)t1t;                       // e ints
    float* ew   = t2t;                             // e floats
    int*   cnt  = (int*)(t2t + e);                 // n
    int*   rp   = cnt + n;                         // n+1
    int*   cur  = rp + n + 1;                      // n
    int*   bsum = cur + n;                         // nb
    int*   boff = bsum + 128;                      // nb

    float* out = (float*)d_out;
    float* out_alpha = out;
    float* out_probs = out + (size_t)n * NC;
    float* out_z     = out + (size_t)2 * n * NC;
    float* out_beta  = out_z + (size_t)n * DLAT;
    float* out_logq  = out_beta + (size_t)n * NC;

    int nb_nodes = (n + 255) / 256;
    int nb_scan = (n + 1023) / 1024;

    hipMemsetAsync(stats, 0, 512 * sizeof(float), stream);

    // encoder
    k_gemm1<<<nb_nodes, 256, 0, stream>>>(x, W1, b1, t1t, n);
    k_stats<<<HDIM * 8, 256, 0, stream>>>(t1t, sum1, sq1, n);
    k_finalize<<<1, 64, 0, stream>>>(sum1, sq1, g1, be1, A1, B1, n);
    k_gemm2<<<nb_nodes, 256, 0, stream>>>(t1t, A1, B1, W2, b2, t2t, n);
    k_stats<<<HDIM * 8, 256, 0, stream>>>(t2t, sum2, sq2, n);
    k_finalize<<<1, 64, 0, stream>>>(sum2, sq2, g2, be2, A2, B2, n);
    k_zflow<<<nb_nodes, 256, 0, stream>>>(t2t, A2, B2, W3, b3, x0, ap, bp, mu, lv,
                                          out_z, out_logq, out_beta, n);

    // CSR build (after zflow: t1t/t2t reusable)
    hipMemsetAsync(cnt, 0, (size_t)n * sizeof(int), stream);
    hipMemsetAsync(cur, 0, (size_t)n * sizeof(int), stream);
    k_count<<<2048, 256, 0, stream>>>(rows, cols, cnt, e, n);
    k_dis<<<nb_nodes, 256, 0, stream>>>(cnt, dis, n);
    k_scan_block<<<nb_scan, 256, 0, stream>>>(cnt, bsum, n);
    k_scan_top<<<1, 64, 0, stream>>>(bsum, boff, nb_scan, rp, n);
    k_scan_write<<<nb_scan, 256, 0, stream>>>(cnt, boff, rp, n);
    k_place<<<2048, 256, 0, stream>>>(rows, cols, dis, rp, cur, ecol, ew, e, n);

    // APPNP: 10 gather rounds, ping-pong h0/h1
    int nb_gather = ((size_t)n * 8 + 255) / 256;
    const float* curh = out_beta;
    for (int it = 0; it < KPROP; ++it) {
        float* outh = (it & 1) ? h1 : h0;
        k_gather<<<nb_gather, 256, 0, stream>>>(rp, ecol, ew, curh, out_beta, dis, outh, n);
        curh = outh;
    }
    k_final<<<nb_nodes, 256, 0, stream>>>(curh, out_alpha, out_probs, n);
}

// Round 3
// 1038.302 us; speedup vs baseline: 12.8770x; 1.2225x over previous
//
#include <hip/hip_runtime.h>

#define NFEAT_IN 256
#define HDIM 64
#define DLAT 16
#define NC 8
#define NL 10
#define KPROP 10
#define ELLW 64
#define OVF_CAP 8192

__device__ __forceinline__ float softplusf(float x) {
    return (x > 20.f) ? x : log1pf(expf(x));
}

// ---------------- encoder (unchanged) ----------------

__global__ __launch_bounds__(256) void k_gemm1(
        const float* __restrict__ x, const float* __restrict__ W1,
        const float* __restrict__ b1, float* __restrict__ t1t, int n) {
    int row = blockIdx.x * 256 + threadIdx.x;
    if (row >= n) return;
    float acc[HDIM];
    #pragma unroll
    for (int j = 0; j < HDIM; ++j) acc[j] = b1[j];
    const float4* x4 = reinterpret_cast<const float4*>(x + (size_t)row * NFEAT_IN);
    for (int k4 = 0; k4 < NFEAT_IN / 4; ++k4) {
        float4 xv = x4[k4];
        const float* w = W1 + k4 * 4 * HDIM;
        #pragma unroll
        for (int j = 0; j < HDIM; ++j) {
            acc[j] += xv.x * w[j] + xv.y * w[HDIM + j]
                    + xv.z * w[2 * HDIM + j] + xv.w * w[3 * HDIM + j];
        }
    }
    #pragma unroll
    for (int j = 0; j < HDIM; ++j) t1t[(size_t)j * n + row] = acc[j];
}

__global__ __launch_bounds__(256) void k_stats(
        const float* __restrict__ tt, float* __restrict__ sum,
        float* __restrict__ sq, int n) {
    int feat = blockIdx.x >> 3;
    int chunk = blockIdx.x & 7;
    const float4* p = reinterpret_cast<const float4*>(tt + (size_t)feat * n);
    int n4 = n / 4;
    float s = 0.f, q = 0.f;
    for (int i = chunk * 256 + threadIdx.x; i < n4; i += 8 * 256) {
        float4 v = p[i];
        s += v.x + v.y + v.z + v.w;
        q += v.x * v.x + v.y * v.y + v.z * v.z + v.w * v.w;
    }
    if (chunk == 0 && threadIdx.x < (n & 3)) {
        float v = tt[(size_t)feat * n + (n & ~3) + threadIdx.x];
        s += v; q += v * v;
    }
    #pragma unroll
    for (int off = 32; off; off >>= 1) {
        s += __shfl_down(s, off, 64);
        q += __shfl_down(q, off, 64);
    }
    __shared__ float ls[4], lq[4];
    int wid = threadIdx.x >> 6, lane = threadIdx.x & 63;
    if (lane == 0) { ls[wid] = s; lq[wid] = q; }
    __syncthreads();
    if (threadIdx.x == 0) {
        atomicAdd(&sum[feat], ls[0] + ls[1] + ls[2] + ls[3]);
        atomicAdd(&sq[feat],  lq[0] + lq[1] + lq[2] + lq[3]);
    }
}

__global__ void k_finalize(const float* __restrict__ sum, const float* __restrict__ sq,
        const float* __restrict__ g, const float* __restrict__ be,
        float* __restrict__ A, float* __restrict__ B, int n) {
    int j = threadIdx.x;
    if (j >= HDIM) return;
    float mean = sum[j] / (float)n;
    float var = sq[j] / (float)n - mean * mean;
    float istd = 1.0f / sqrtf(var + 1e-5f);
    A[j] = g[j] * istd;
    B[j] = be[j] - mean * istd * g[j];
}

__global__ __launch_bounds__(256) void k_gemm2(
        const float* __restrict__ t1t, const float* __restrict__ A1,
        const float* __restrict__ B1, const float* __restrict__ W2,
        const float* __restrict__ b2, float* __restrict__ t2t, int n) {
    int row = blockIdx.x * 256 + threadIdx.x;
    if (row >= n) return;
    float acc[HDIM];
    #pragma unroll
    for (int j = 0; j < HDIM; ++j) acc[j] = b2[j];
    for (int k = 0; k < HDIM; ++k) {
        float hv = fmaxf(A1[k] * t1t[(size_t)k * n + row] + B1[k], 0.f);
        const float* w = W2 + k * HDIM;
        #pragma unroll
        for (int j = 0; j < HDIM; ++j) acc[j] += hv * w[j];
    }
    #pragma unroll
    for (int j = 0; j < HDIM; ++j) t2t[(size_t)j * n + row] = acc[j];
}

__global__ __launch_bounds__(256) void k_zflow(
        const float* __restrict__ t2t, const float* __restrict__ A2,
        const float* __restrict__ B2, const float* __restrict__ W3,
        const float* __restrict__ b3, const float* __restrict__ x0,
        const float* __restrict__ ap, const float* __restrict__ bp,
        const float* __restrict__ mu, const float* __restrict__ lv,
        float* __restrict__ out_z, float* __restrict__ out_logq,
        float* __restrict__ out_beta, int n) {
    __shared__ float a_s[NL * NC], b_s[NL * NC], x0_s[NL * NC * DLAT];
    __shared__ float mu_s[NC * DLAT], iv_s[NC * DLAT], slv_s[NC];
    for (int i = threadIdx.x; i < NL * NC; i += 256) {
        float a = softplusf(ap[i]);
        a_s[i] = a;
        b_s[i] = softplusf(bp[i]) - a;
    }
    for (int i = threadIdx.x; i < NL * NC * DLAT; i += 256) x0_s[i] = x0[i];
    for (int i = threadIdx.x; i < NC * DLAT; i += 256) {
        mu_s[i] = mu[i];
        iv_s[i] = expf(-lv[i]);
    }
    if (threadIdx.x < NC) {
        float s = 0.f;
        for (int d = 0; d < DLAT; ++d) s += lv[threadIdx.x * DLAT + d];
        slv_s[threadIdx.x] = s;
    }
    __syncthreads();
    int row = blockIdx.x * 256 + threadIdx.x;
    if (row >= n) return;
    float z[DLAT];
    #pragma unroll
    for (int j = 0; j < DLAT; ++j) z[j] = b3[j];
    for (int k = 0; k < HDIM; ++k) {
        float hv = fmaxf(A2[k] * t2t[(size_t)k * n + row] + B2[k], 0.f);
        const float* w = W3 + k * DLAT;
        #pragma unroll
        for (int j = 0; j < DLAT; ++j) z[j] += hv * w[j];
    }
    #pragma unroll
    for (int j = 0; j < DLAT; ++j) out_z[(size_t)row * DLAT + j] = z[j];

    for (int c = 0; c < NC; ++c) {
        float zz[DLAT];
        #pragma unroll
        for (int d = 0; d < DLAT; ++d) zz[d] = z[d];
        float log_det = 0.f;
        for (int l = NL - 1; l >= 0; --l) {
            float a = a_s[l * NC + c], b = b_s[l * NC + c];
            const float* x0p = &x0_s[(l * NC + c) * DLAT];
            float diff[DLAT];
            float r2 = 0.f;
            #pragma unroll
            for (int d = 0; d < DLAT; ++d) {
                diff[d] = zz[d] - x0p[d];
                r2 += diff[d] * diff[d];
            }
            float r = fmaxf(sqrtf(r2), 1e-8f);
            float h = 1.f / (a + r);
            float bh = b * h;
            #pragma unroll
            for (int d = 0; d < DLAT; ++d) zz[d] += bh * diff[d];
            log_det += (DLAT - 1) * log1pf(bh) + log1pf(bh - bh * h * r);
        }
        float quad = 0.f;
        #pragma unroll
        for (int d = 0; d < DLAT; ++d) {
            float dd = zz[d] - mu_s[c * DLAT + d];
            quad += dd * dd * iv_s[c * DLAT + d];
        }
        float lq = -14.70301653f - 0.5f * slv_s[c] - 0.5f * quad + log_det;
        out_logq[(size_t)row * NC + c] = lq;
        float w = fminf(fmaxf(lq + 20.24819398f, -30.f), 30.f);
        out_beta[(size_t)row * NC + c] = expf(w);
    }
}

// ---------------- single-pass ELL build ----------------

__global__ __launch_bounds__(256) void k_place(
        const int* __restrict__ rows, const int* __restrict__ colsrc,
        int* __restrict__ cur, int* __restrict__ ecol,
        int2* __restrict__ ovf, int* __restrict__ ovf_cnt, int e, int n) {
    int stride = gridDim.x * blockDim.x;
    for (int i = blockIdx.x * blockDim.x + threadIdx.x; i < e; i += stride) {
        int r = rows[i], c = colsrc[i];
        if ((unsigned)r >= (unsigned)n || (unsigned)c >= (unsigned)n) continue;
        int j = atomicAdd(&cur[r], 1);
        if (j < ELLW) {
            ecol[(size_t)r * ELLW + j] = c;
        } else {
            int o = atomicAdd(ovf_cnt, 1);
            if (o < OVF_CAP) ovf[o] = make_int2(r, c);
        }
    }
}

__global__ void k_dis(const int* __restrict__ cur, float* __restrict__ dis, int n) {
    int i = blockIdx.x * blockDim.x + threadIdx.x;
    if (i < n) dis[i] = rsqrtf((float)cur[i] + 1.0f);   // +1 = self loop
}

// hs0 = dis * beta
__global__ void k_init_hs(const float* __restrict__ beta, const float* __restrict__ dis,
                          float* __restrict__ hs, int n) {
    int i = blockIdx.x * blockDim.x + threadIdx.x;
    if (i >= n) return;
    float d = dis[i];
    const float4* b = reinterpret_cast<const float4*>(beta + (size_t)i * NC);
    float4* o = reinterpret_cast<float4*>(hs + (size_t)i * NC);
    float4 b0 = b[0], b1 = b[1];
    o[0] = make_float4(d * b0.x, d * b0.y, d * b0.z, d * b0.w);
    o[1] = make_float4(d * b1.x, d * b1.y, d * b1.z, d * b1.w);
}

// ---------------- APPNP gather iteration ----------------
// msg[r] = dis[r] * (hs[r] + sum_edges hs[col]);  hnew = 0.9*msg + 0.1*beta;
// hs_out = dis * hnew.  8 lanes per row (one per class channel).
__global__ __launch_bounds__(256) void k_gather(
        const int* __restrict__ cur, const int* __restrict__ ecol,
        const float* __restrict__ hs_in, const float* __restrict__ beta,
        const float* __restrict__ dis, float* __restrict__ hout,
        float* __restrict__ hs_out, int n) {
    int row = (blockIdx.x * blockDim.x + threadIdx.x) >> 3;
    int c = threadIdx.x & 7;
    if (row >= n) return;
    int cnt = cur[row]; if (cnt > ELLW) cnt = ELLW;
    float d = dis[row];
    const int* ec = ecol + (size_t)row * ELLW;
    float acc = hs_in[row * NC + c];   // self loop (dis^2*h = dis*hs)
    for (int ep = 0; ep < cnt; ++ep) {
        int cl = ec[ep];
        acc += hs_in[cl * NC + c];
    }
    float hn = 0.9f * d * acc + 0.1f * beta[row * NC + c];
    hout[row * NC + c] = hn;
    hs_out[row * NC + c] = d * hn;
}

// correctness parachute for rows with degree > ELLW (expected empty)
__global__ void k_ovf(const int2* __restrict__ ovf, const int* __restrict__ ovf_cnt,
                      const float* __restrict__ dis, const float* __restrict__ hs_in,
                      float* __restrict__ hout, float* __restrict__ hs_out) {
    int m = *ovf_cnt; if (m > OVF_CAP) m = OVF_CAP;
    int idx = threadIdx.x >> 3;
    int c = threadIdx.x & 7;
    for (int i = idx; i < m; i += 32) {
        int r = ovf[i].x, cl = ovf[i].y;
        float d = dis[r];
        float contrib = 0.9f * d * hs_in[cl * NC + c];
        atomicAdd(&hout[r * NC + c], contrib);
        atomicAdd(&hs_out[r * NC + c], contrib * d);
    }
}

__global__ void k_final(const float* __restrict__ h, float* __restrict__ out_alpha,
        float* __restrict__ out_probs, int n) {
    int i = blockIdx.x * blockDim.x + threadIdx.x;
    if (i >= n) return;
    float a[NC];
    float s = 0.f;
    #pragma unroll
    for (int c = 0; c < NC; ++c) {
        float v = h[(size_t)i * NC + c];
        v = 0.001f + fmaxf(v, 0.f);
        a[c] = v; s += v;
    }
    float inv = 1.f / s;
    #pragma unroll
    for (int c = 0; c < NC; ++c) {
        out_alpha[(size_t)i * NC + c] = a[c];
        out_probs[(size_t)i * NC + c] = a[c] * inv;
    }
}

extern "C" void kernel_launch(void* const* d_in, const int* in_sizes, int n_in,
                              void* d_out, int out_size, void* d_ws, size_t ws_size,
                              hipStream_t stream) {
    const float* x   = (const float*)d_in[0];
    const int*   ei  = (const int*)d_in[1];
    const float* W1  = (const float*)d_in[2];
    const float* b1  = (const float*)d_in[3];
    const float* g1  = (const float*)d_in[4];
    const float* be1 = (const float*)d_in[5];
    const float* W2  = (const float*)d_in[6];
    const float* b2  = (const float*)d_in[7];
    const float* g2  = (const float*)d_in[8];
    const float* be2 = (const float*)d_in[9];
    const float* W3  = (const float*)d_in[10];
    const float* b3  = (const float*)d_in[11];
    const float* x0  = (const float*)d_in[12];
    const float* ap  = (const float*)d_in[13];
    const float* bp  = (const float*)d_in[14];
    const float* mu  = (const float*)d_in[15];
    const float* lv  = (const float*)d_in[16];

    int n = in_sizes[0] / NFEAT_IN;   // 100000
    int e = in_sizes[1] / 2;          // 3200000
    const int* rows = ei;
    const int* cols = ei + e;

    float* ws = (float*)d_ws;
    float* t1t = ws;                               // 64*n floats
    float* t2t = t1t + (size_t)HDIM * n;           // 64*n floats
    float* hs0 = t2t + (size_t)HDIM * n;           // 8*n
    float* hs1 = hs0 + (size_t)NC * n;             // 8*n
    float* stats = hs1 + (size_t)NC * n;           // 512
    float *sum1 = stats,       *sq1 = stats + 64,  *A1 = stats + 128, *B1 = stats + 192;
    float *sum2 = stats + 256, *sq2 = stats + 320, *A2 = stats + 384, *B2 = stats + 448;
    int*  ovf_cnt = (int*)(stats + 512);           // 1 (+pad)
    int2* ovf     = (int2*)(ovf_cnt + 4);          // OVF_CAP int2

    // ELL col array overlays t1t/t2t (dead after k_zflow): 64*n ints
    int* ecol = (int*)t1t;

    float* out = (float*)d_out;
    float* out_alpha = out;                        // doubles as hout during APPNP
    float* out_probs = out + (size_t)n * NC;       // scratch for cur/dis until k_final
    float* out_z     = out + (size_t)2 * n * NC;
    float* out_beta  = out_z + (size_t)n * DLAT;
    float* out_logq  = out_beta + (size_t)n * NC;

    int*   cur = (int*)out_probs;                  // n ints
    float* dis = out_probs + n;                    // n floats

    int nb_nodes = (n + 255) / 256;

    hipMemsetAsync(stats, 0, 512 * sizeof(float), stream);

    // encoder
    k_gemm1<<<nb_nodes, 256, 0, stream>>>(x, W1, b1, t1t, n);
    k_stats<<<HDIM * 8, 256, 0, stream>>>(t1t, sum1, sq1, n);
    k_finalize<<<1, 64, 0, stream>>>(sum1, sq1, g1, be1, A1, B1, n);
    k_gemm2<<<nb_nodes, 256, 0, stream>>>(t1t, A1, B1, W2, b2, t2t, n);
    k_stats<<<HDIM * 8, 256, 0, stream>>>(t2t, sum2, sq2, n);
    k_finalize<<<1, 64, 0, stream>>>(sum2, sq2, g2, be2, A2, B2, n);
    k_zflow<<<nb_nodes, 256, 0, stream>>>(t2t, A2, B2, W3, b3, x0, ap, bp, mu, lv,
                                          out_z, out_logq, out_beta, n);

    // ELL build (t1t/t2t dead now)
    hipMemsetAsync(cur, 0, (size_t)n * sizeof(int), stream);
    hipMemsetAsync(ovf_cnt, 0, sizeof(int), stream);
    k_place<<<2048, 256, 0, stream>>>(rows, cols, cur, ecol, ovf, ovf_cnt, e, n);
    k_dis<<<nb_nodes, 256, 0, stream>>>(cur, dis, n);
    k_init_hs<<<nb_nodes, 256, 0, stream>>>(out_beta, dis, hs0, n);

    // APPNP: 10 gather rounds, ping-pong hs0/hs1; hout lives in out_alpha
    int nb_gather = ((size_t)n * 8 + 255) / 256;
    for (int it = 0; it < KPROP; ++it) {
        const float* hin = (it & 1) ? hs1 : hs0;
        float* hso = (it & 1) ? hs0 : hs1;
        k_gather<<<nb_gather, 256, 0, stream>>>(cur, ecol, hin, out_beta, dis,
                                                out_alpha, hso, n);
        k_ovf<<<1, 256, 0, stream>>>(ovf, ovf_cnt, dis, hin, out_alpha, hso);
    }
    k_final<<<nb_nodes, 256, 0, stream>>>(out_alpha, out_alpha, out_probs, n);
}

// Round 4
// 815.684 us; speedup vs baseline: 16.3915x; 1.2729x over previous
//
#include <hip/hip_runtime.h>

#define NFEAT_IN 256
#define HDIM 64
#define DLAT 16
#define NC 8
#define NL 10
#define KPROP 10
#define ELLW 64
#define OVF_CAP 8192
#define NB 128          // row-range buckets
#define PERTHREAD 16
#define TILE (256 * PERTHREAD)

__device__ __forceinline__ float softplusf(float x) {
    return (x > 20.f) ? x : log1pf(expf(x));
}

// ---------------- encoder (unchanged) ----------------

__global__ __launch_bounds__(256) void k_gemm1(
        const float* __restrict__ x, const float* __restrict__ W1,
        const float* __restrict__ b1, float* __restrict__ t1t, int n) {
    int row = blockIdx.x * 256 + threadIdx.x;
    if (row >= n) return;
    float acc[HDIM];
    #pragma unroll
    for (int j = 0; j < HDIM; ++j) acc[j] = b1[j];
    const float4* x4 = reinterpret_cast<const float4*>(x + (size_t)row * NFEAT_IN);
    for (int k4 = 0; k4 < NFEAT_IN / 4; ++k4) {
        float4 xv = x4[k4];
        const float* w = W1 + k4 * 4 * HDIM;
        #pragma unroll
        for (int j = 0; j < HDIM; ++j) {
            acc[j] += xv.x * w[j] + xv.y * w[HDIM + j]
                    + xv.z * w[2 * HDIM + j] + xv.w * w[3 * HDIM + j];
        }
    }
    #pragma unroll
    for (int j = 0; j < HDIM; ++j) t1t[(size_t)j * n + row] = acc[j];
}

__global__ __launch_bounds__(256) void k_stats(
        const float* __restrict__ tt, float* __restrict__ sum,
        float* __restrict__ sq, int n) {
    int feat = blockIdx.x >> 3;
    int chunk = blockIdx.x & 7;
    const float4* p = reinterpret_cast<const float4*>(tt + (size_t)feat * n);
    int n4 = n / 4;
    float s = 0.f, q = 0.f;
    for (int i = chunk * 256 + threadIdx.x; i < n4; i += 8 * 256) {
        float4 v = p[i];
        s += v.x + v.y + v.z + v.w;
        q += v.x * v.x + v.y * v.y + v.z * v.z + v.w * v.w;
    }
    if (chunk == 0 && threadIdx.x < (n & 3)) {
        float v = tt[(size_t)feat * n + (n & ~3) + threadIdx.x];
        s += v; q += v * v;
    }
    #pragma unroll
    for (int off = 32; off; off >>= 1) {
        s += __shfl_down(s, off, 64);
        q += __shfl_down(q, off, 64);
    }
    __shared__ float ls[4], lq[4];
    int wid = threadIdx.x >> 6, lane = threadIdx.x & 63;
    if (lane == 0) { ls[wid] = s; lq[wid] = q; }
    __syncthreads();
    if (threadIdx.x == 0) {
        atomicAdd(&sum[feat], ls[0] + ls[1] + ls[2] + ls[3]);
        atomicAdd(&sq[feat],  lq[0] + lq[1] + lq[2] + lq[3]);
    }
}

__global__ void k_finalize(const float* __restrict__ sum, const float* __restrict__ sq,
        const float* __restrict__ g, const float* __restrict__ be,
        float* __restrict__ A, float* __restrict__ B, int n) {
    int j = threadIdx.x;
    if (j >= HDIM) return;
    float mean = sum[j] / (float)n;
    float var = sq[j] / (float)n - mean * mean;
    float istd = 1.0f / sqrtf(var + 1e-5f);
    A[j] = g[j] * istd;
    B[j] = be[j] - mean * istd * g[j];
}

__global__ __launch_bounds__(256) void k_gemm2(
        const float* __restrict__ t1t, const float* __restrict__ A1,
        const float* __restrict__ B1, const float* __restrict__ W2,
        const float* __restrict__ b2, float* __restrict__ t2t, int n) {
    int row = blockIdx.x * 256 + threadIdx.x;
    if (row >= n) return;
    float acc[HDIM];
    #pragma unroll
    for (int j = 0; j < HDIM; ++j) acc[j] = b2[j];
    for (int k = 0; k < HDIM; ++k) {
        float hv = fmaxf(A1[k] * t1t[(size_t)k * n + row] + B1[k], 0.f);
        const float* w = W2 + k * HDIM;
        #pragma unroll
        for (int j = 0; j < HDIM; ++j) acc[j] += hv * w[j];
    }
    #pragma unroll
    for (int j = 0; j < HDIM; ++j) t2t[(size_t)j * n + row] = acc[j];
}

__global__ __launch_bounds__(256) void k_zflow(
        const float* __restrict__ t2t, const float* __restrict__ A2,
        const float* __restrict__ B2, const float* __restrict__ W3,
        const float* __restrict__ b3, const float* __restrict__ x0,
        const float* __restrict__ ap, const float* __restrict__ bp,
        const float* __restrict__ mu, const float* __restrict__ lv,
        float* __restrict__ out_z, float* __restrict__ out_logq,
        float* __restrict__ out_beta, int n) {
    __shared__ float a_s[NL * NC], b_s[NL * NC], x0_s[NL * NC * DLAT];
    __shared__ float mu_s[NC * DLAT], iv_s[NC * DLAT], slv_s[NC];
    for (int i = threadIdx.x; i < NL * NC; i += 256) {
        float a = softplusf(ap[i]);
        a_s[i] = a;
        b_s[i] = softplusf(bp[i]) - a;
    }
    for (int i = threadIdx.x; i < NL * NC * DLAT; i += 256) x0_s[i] = x0[i];
    for (int i = threadIdx.x; i < NC * DLAT; i += 256) {
        mu_s[i] = mu[i];
        iv_s[i] = expf(-lv[i]);
    }
    if (threadIdx.x < NC) {
        float s = 0.f;
        for (int d = 0; d < DLAT; ++d) s += lv[threadIdx.x * DLAT + d];
        slv_s[threadIdx.x] = s;
    }
    __syncthreads();
    int row = blockIdx.x * 256 + threadIdx.x;
    if (row >= n) return;
    float z[DLAT];
    #pragma unroll
    for (int j = 0; j < DLAT; ++j) z[j] = b3[j];
    for (int k = 0; k < HDIM; ++k) {
        float hv = fmaxf(A2[k] * t2t[(size_t)k * n + row] + B2[k], 0.f);
        const float* w = W3 + k * DLAT;
        #pragma unroll
        for (int j = 0; j < DLAT; ++j) z[j] += hv * w[j];
    }
    #pragma unroll
    for (int j = 0; j < DLAT; ++j) out_z[(size_t)row * DLAT + j] = z[j];

    for (int c = 0; c < NC; ++c) {
        float zz[DLAT];
        #pragma unroll
        for (int d = 0; d < DLAT; ++d) zz[d] = z[d];
        float log_det = 0.f;
        for (int l = NL - 1; l >= 0; --l) {
            float a = a_s[l * NC + c], b = b_s[l * NC + c];
            const float* x0p = &x0_s[(l * NC + c) * DLAT];
            float diff[DLAT];
            float r2 = 0.f;
            #pragma unroll
            for (int d = 0; d < DLAT; ++d) {
                diff[d] = zz[d] - x0p[d];
                r2 += diff[d] * diff[d];
            }
            float r = fmaxf(sqrtf(r2), 1e-8f);
            float h = 1.f / (a + r);
            float bh = b * h;
            #pragma unroll
            for (int d = 0; d < DLAT; ++d) zz[d] += bh * diff[d];
            log_det += (DLAT - 1) * log1pf(bh) + log1pf(bh - bh * h * r);
        }
        float quad = 0.f;
        #pragma unroll
        for (int d = 0; d < DLAT; ++d) {
            float dd = zz[d] - mu_s[c * DLAT + d];
            quad += dd * dd * iv_s[c * DLAT + d];
        }
        float lq = -14.70301653f - 0.5f * slv_s[c] - 0.5f * quad + log_det;
        out_logq[(size_t)row * NC + c] = lq;
        float w = fminf(fmaxf(lq + 20.24819398f, -30.f), 30.f);
        out_beta[(size_t)row * NC + c] = expf(w);
    }
}

// ---------------- pass 1: radix partition edges into NB row-range buckets ----
// LDS-staged so global writes are coalesced runs per bucket.
__global__ __launch_bounds__(256) void k_bucket(
        const int* __restrict__ rows, const int* __restrict__ cols,
        int2* __restrict__ bpairs, int* __restrict__ bcnt, int cap,
        int* __restrict__ cur, int2* __restrict__ ovf, int* __restrict__ ovf_cnt,
        int e, int n, int rpb) {
    __shared__ int lcnt[NB], loff[NB], lcur[NB], gbase[NB], sc[NB];
    __shared__ int2 staged[TILE];
    int t = threadIdx.x;
    int base = blockIdx.x * TILE;
    for (int i = t; i < NB; i += 256) lcnt[i] = 0;
    __syncthreads();
    int er[PERTHREAD], ec[PERTHREAD], eb[PERTHREAD];
    #pragma unroll
    for (int k = 0; k < PERTHREAD; ++k) {
        int i = base + k * 256 + t;
        eb[k] = -1;
        if (i < e) {
            int r = rows[i], c = cols[i];
            if ((unsigned)r < (unsigned)n && (unsigned)c < (unsigned)n) {
                er[k] = r; ec[k] = c;
                int b = (int)((unsigned)r / (unsigned)rpb);
                eb[k] = b;
                atomicAdd(&lcnt[b], 1);
            }
        }
    }
    __syncthreads();
    if (t < NB) sc[t] = lcnt[t];
    __syncthreads();
    for (int off = 1; off < NB; off <<= 1) {
        int v = 0;
        if (t < NB && t >= off) v = sc[t - off];
        __syncthreads();
        if (t < NB) sc[t] += v;
        __syncthreads();
    }
    if (t < NB) { loff[t] = sc[t] - lcnt[t]; lcur[t] = sc[t] - lcnt[t]; }
    __syncthreads();
    #pragma unroll
    for (int k = 0; k < PERTHREAD; ++k) {
        if (eb[k] >= 0) {
            int slot = atomicAdd(&lcur[eb[k]], 1);
            staged[slot] = make_int2(er[k], ec[k]);
        }
    }
    __syncthreads();
    if (t < NB && lcnt[t] > 0) gbase[t] = atomicAdd(&bcnt[t], lcnt[t]);
    __syncthreads();
    int wid = t >> 6, lane = t & 63;
    for (int b = wid; b < NB; b += 4) {
        int cnt = lcnt[b];
        if (!cnt) continue;
        int gb = gbase[b], lo = loff[b];
        for (int k = lane; k < cnt; k += 64) {
            int2 p = staged[lo + k];
            int dst = gb + k;
            if (dst < cap) {
                bpairs[(size_t)b * cap + dst] = p;
            } else {   // bucket overflow parachute (>=9 sigma, expected never)
                int o = atomicAdd(ovf_cnt, 1);
                if (o < OVF_CAP) ovf[o] = p;
                atomicAdd(&cur[p.x], 1);   // keep degree correct
            }
        }
    }
}

// ---------------- pass 2: per-bucket ELL placement (L2-local writes) --------
// Requires rpb <= 1024 (n <= 131072 for NB=128).
__global__ __launch_bounds__(256) void k_build(
        const int2* __restrict__ bpairs, const int* __restrict__ bcnt, int cap,
        int* __restrict__ ecol, int* __restrict__ cur,
        int2* __restrict__ ovf, int* __restrict__ ovf_cnt, int n, int rpb) {
    __shared__ int lcnt[1024];
    int b = blockIdx.x, t = threadIdx.x;
    int row_base = b * rpb;
    int nrows = n - row_base; if (nrows > rpb) nrows = rpb;
    if (nrows <= 0) return;
    for (int i = t; i < nrows; i += 256) lcnt[i] = 0;
    __syncthreads();
    int m = bcnt[b]; if (m > cap) m = cap;
    const int2* bp = bpairs + (size_t)b * cap;
    for (int i = t; i < m; i += 256) {
        int2 p = bp[i];
        int lr = p.x - row_base;
        int j = atomicAdd(&lcnt[lr], 1);
        if (j < ELLW) {
            ecol[(size_t)p.x * ELLW + j] = p.y;
        } else {   // row-degree overflow parachute
            int o = atomicAdd(ovf_cnt, 1);
            if (o < OVF_CAP) ovf[o] = p;
        }
    }
    __syncthreads();
    for (int i = t; i < nrows; i += 256) {
        int c = lcnt[i];
        if (c) cur[row_base + i] += c;   // merge with pass-1 overflow increments
    }
}

__global__ void k_dis(const int* __restrict__ cur, float* __restrict__ dis, int n) {
    int i = blockIdx.x * blockDim.x + threadIdx.x;
    if (i < n) dis[i] = rsqrtf((float)cur[i] + 1.0f);   // +1 = self loop
}

__global__ void k_init_hs(const float* __restrict__ beta, const float* __restrict__ dis,
                          float* __restrict__ hs, int n) {
    int i = blockIdx.x * blockDim.x + threadIdx.x;
    if (i >= n) return;
    float d = dis[i];
    const float4* b = reinterpret_cast<const float4*>(beta + (size_t)i * NC);
    float4* o = reinterpret_cast<float4*>(hs + (size_t)i * NC);
    float4 b0 = b[0], b1 = b[1];
    o[0] = make_float4(d * b0.x, d * b0.y, d * b0.z, d * b0.w);
    o[1] = make_float4(d * b1.x, d * b1.y, d * b1.z, d * b1.w);
}

// ---------------- APPNP gather iteration ----------------
// msg[r] = dis[r]*(hs[r] + sum hs[col]);  hnew = 0.9*msg + 0.1*beta; hs_out = dis*hnew.
__global__ __launch_bounds__(256) void k_gather(
        const int* __restrict__ cur, const int* __restrict__ ecol,
        const float* __restrict__ hs_in, const float* __restrict__ beta,
        const float* __restrict__ dis, float* __restrict__ hout,
        float* __restrict__ hs_out, const int2* __restrict__ ovf,
        const int* __restrict__ ovf_cnt, int n) {
    int row = (blockIdx.x * blockDim.x + threadIdx.x) >> 3;
    int c = threadIdx.x & 7;
    if (row >= n) return;
    int cnt = cur[row];
    int lim = cnt < ELLW ? cnt : ELLW;
    float d = dis[row];
    const int* ec = ecol + (size_t)row * ELLW;
    float acc = hs_in[row * NC + c];   // self loop
    for (int ep = 0; ep < lim; ++ep) acc += hs_in[ec[ep] * NC + c];
    int m = *ovf_cnt;
    if (m > 0) {   // parachute: expected never taken
        if (m > OVF_CAP) m = OVF_CAP;
        for (int i = 0; i < m; ++i) {
            int2 p = ovf[i];
            if (p.x == row) acc += hs_in[p.y * NC + c];
        }
    }
    float hn = 0.9f * d * acc + 0.1f * beta[row * NC + c];
    hout[row * NC + c] = hn;
    hs_out[row * NC + c] = d * hn;
}

__global__ void k_final(const float* __restrict__ h, float* __restrict__ out_alpha,
        float* __restrict__ out_probs, int n) {
    int i = blockIdx.x * blockDim.x + threadIdx.x;
    if (i >= n) return;
    float a[NC];
    float s = 0.f;
    #pragma unroll
    for (int c = 0; c < NC; ++c) {
        float v = h[(size_t)i * NC + c];
        v = 0.001f + fmaxf(v, 0.f);
        a[c] = v; s += v;
    }
    float inv = 1.f / s;
    #pragma unroll
    for (int c = 0; c < NC; ++c) {
        out_alpha[(size_t)i * NC + c] = a[c];
        out_probs[(size_t)i * NC + c] = a[c] * inv;
    }
}

extern "C" void kernel_launch(void* const* d_in, const int* in_sizes, int n_in,
                              void* d_out, int out_size, void* d_ws, size_t ws_size,
                              hipStream_t stream) {
    const float* x   = (const float*)d_in[0];
    const int*   ei  = (const int*)d_in[1];
    const float* W1  = (const float*)d_in[2];
    const float* b1  = (const float*)d_in[3];
    const float* g1  = (const float*)d_in[4];
    const float* be1 = (const float*)d_in[5];
    const float* W2  = (const float*)d_in[6];
    const float* b2  = (const float*)d_in[7];
    const float* g2  = (const float*)d_in[8];
    const float* be2 = (const float*)d_in[9];
    const float* W3  = (const float*)d_in[10];
    const float* b3  = (const float*)d_in[11];
    const float* x0  = (const float*)d_in[12];
    const float* ap  = (const float*)d_in[13];
    const float* bp  = (const float*)d_in[14];
    const float* mu  = (const float*)d_in[15];
    const float* lv  = (const float*)d_in[16];

    int n = in_sizes[0] / NFEAT_IN;   // 100000
    int e = in_sizes[1] / 2;          // 3200000
    const int* rows = ei;
    const int* cols = ei + e;
    int rpb = (n + NB - 1) / NB;      // 782 rows per bucket
    int cap = (e + e / 16) / NB;      // 26562 pairs/bucket (+9.9 sigma slack)

    size_t an = (size_t)HDIM * n;
    float* ws  = (float*)d_ws;
    float* t1t = ws;                         // 64n floats; later ecol (64n ints)
    float* t2t = ws + an;                    // 64n floats; later bucket pairs
    int2*  bpairs = (int2*)t2t;              // NB*cap int2 (27.2 MB, extends past t2t)
    float* stats = (float*)((char*)t2t + (size_t)NB * cap * sizeof(int2));
    float *sum1 = stats,       *sq1 = stats + 64,  *A1 = stats + 128, *B1 = stats + 192;
    float *sum2 = stats + 256, *sq2 = stats + 320, *A2 = stats + 384, *B2 = stats + 448;
    int*  bcnt    = (int*)(stats + 512);     // NB
    int*  ovf_cnt = bcnt + NB;               // 1 (+pad)
    int2* ovf     = (int2*)(ovf_cnt + 4);    // OVF_CAP int2
    // hs ping-pong overlays dead bucket region after k_build
    float* hs0 = (float*)bpairs;
    float* hs1 = hs0 + (size_t)NC * n;
    int* ecol = (int*)t1t;

    float* out = (float*)d_out;
    float* out_alpha = out;                  // doubles as hout during APPNP
    float* out_probs = out + (size_t)n * NC; // holds cur/dis until k_final
    float* out_z     = out + (size_t)2 * n * NC;
    float* out_beta  = out_z + (size_t)n * DLAT;
    float* out_logq  = out_beta + (size_t)n * NC;

    int*   cur = (int*)out_probs;            // n ints
    float* dis = out_probs + n;              // n floats

    int nb_nodes = (n + 255) / 256;

    hipMemsetAsync(stats, 0, (512 + NB + 4) * sizeof(float), stream);

    // encoder
    k_gemm1<<<nb_nodes, 256, 0, stream>>>(x, W1, b1, t1t, n);
    k_stats<<<HDIM * 8, 256, 0, stream>>>(t1t, sum1, sq1, n);
    k_finalize<<<1, 64, 0, stream>>>(sum1, sq1, g1, be1, A1, B1, n);
    k_gemm2<<<nb_nodes, 256, 0, stream>>>(t1t, A1, B1, W2, b2, t2t, n);
    k_stats<<<HDIM * 8, 256, 0, stream>>>(t2t, sum2, sq2, n);
    k_finalize<<<1, 64, 0, stream>>>(sum2, sq2, g2, be2, A2, B2, n);
    k_zflow<<<nb_nodes, 256, 0, stream>>>(t2t, A2, B2, W3, b3, x0, ap, bp, mu, lv,
                                          out_z, out_logq, out_beta, n);

    // graph build: radix partition then per-bucket ELL placement
    hipMemsetAsync(cur, 0, (size_t)n * sizeof(int), stream);
    int nt_bucket = (e + TILE - 1) / TILE;
    k_bucket<<<nt_bucket, 256, 0, stream>>>(rows, cols, bpairs, bcnt, cap,
                                            cur, ovf, ovf_cnt, e, n, rpb);
    k_build<<<NB, 256, 0, stream>>>(bpairs, bcnt, cap, ecol, cur, ovf, ovf_cnt, n, rpb);
    k_dis<<<nb_nodes, 256, 0, stream>>>(cur, dis, n);
    k_init_hs<<<nb_nodes, 256, 0, stream>>>(out_beta, dis, hs0, n);

    // APPNP: 10 gather rounds, ping-pong hs0/hs1; hout lives in out_alpha
    int nb_gather = (int)(((size_t)n * 8 + 255) / 256);
    for (int it = 0; it < KPROP; ++it) {
        const float* hin = (it & 1) ? hs1 : hs0;
        float* hso = (it & 1) ? hs0 : hs1;
        k_gather<<<nb_gather, 256, 0, stream>>>(cur, ecol, hin, out_beta, dis,
                                                out_alpha, hso, ovf, ovf_cnt, n);
    }
    k_final<<<nb_nodes, 256, 0, stream>>>(out_alpha, out_alpha, out_probs, n);
}

// Round 5
// 773.876 us; speedup vs baseline: 17.2770x; 1.0540x over previous
//
#include <hip/hip_runtime.h>

#define NFEAT_IN 256
#define HDIM 64
#define DLAT 16
#define NC 8
#define NL 10
#define KPROP 10
#define ELLW 64
#define OVF_CAP 8192
#define NB 128          // row-range buckets
#define PERTHREAD 16
#define TILE (256 * PERTHREAD)
#define BM 64           // GEMM row tile
#define BKT 64          // GEMM k tile

__device__ __forceinline__ float softplusf(float x) {
    return (x > 20.f) ? x : log1pf(expf(x));
}

// ---------------- tiled GEMM1: x[n][256] @ W1[256][64] + b1 -> t1t[64][n] ----
__global__ __launch_bounds__(256) void k_gemm1(
        const float* __restrict__ x, const float* __restrict__ W1,
        const float* __restrict__ b1, float* __restrict__ t1t, int n) {
    __shared__ float xs[BKT][BM + 4];   // [k][row], +4 keeps 16B alignment
    __shared__ float ws[BKT][HDIM];     // [k][j]
    int t = threadIdx.x;
    int row0 = blockIdx.x * BM;
    int tr = t >> 4, tc = t & 15;       // 16x16 thread grid; 4x4 micro-tile
    float acc[4][4];
    float4 bv = *reinterpret_cast<const float4*>(&b1[tc * 4]);
    #pragma unroll
    for (int i = 0; i < 4; ++i) {
        acc[i][0] = bv.x; acc[i][1] = bv.y; acc[i][2] = bv.z; acc[i][3] = bv.w;
    }
    for (int k0 = 0; k0 < NFEAT_IN; k0 += BKT) {
        __syncthreads();
        // stage x tile transposed: 64 rows x 64 k
        #pragma unroll
        for (int it = 0; it < 4; ++it) {
            int i = it * 256 + t;
            int row = i >> 4, q = i & 15;
            int grow = row0 + row;
            float4 v = make_float4(0.f, 0.f, 0.f, 0.f);
            if (grow < n)
                v = *reinterpret_cast<const float4*>(
                        &x[(size_t)grow * NFEAT_IN + k0 + q * 4]);
            xs[q * 4 + 0][row] = v.x;
            xs[q * 4 + 1][row] = v.y;
            xs[q * 4 + 2][row] = v.z;
            xs[q * 4 + 3][row] = v.w;
        }
        // stage W tile
        #pragma unroll
        for (int it = 0; it < 4; ++it) {
            int i = it * 256 + t;
            int kk = i >> 4, q = i & 15;
            *reinterpret_cast<float4*>(&ws[kk][q * 4]) =
                *reinterpret_cast<const float4*>(&W1[(size_t)(k0 + kk) * HDIM + q * 4]);
        }
        __syncthreads();
        #pragma unroll 8
        for (int kk = 0; kk < BKT; ++kk) {
            float4 a = *reinterpret_cast<const float4*>(&xs[kk][tr * 4]);
            float4 w = *reinterpret_cast<const float4*>(&ws[kk][tc * 4]);
            acc[0][0] += a.x * w.x; acc[0][1] += a.x * w.y;
            acc[0][2] += a.x * w.z; acc[0][3] += a.x * w.w;
            acc[1][0] += a.y * w.x; acc[1][1] += a.y * w.y;
            acc[1][2] += a.y * w.z; acc[1][3] += a.y * w.w;
            acc[2][0] += a.z * w.x; acc[2][1] += a.z * w.y;
            acc[2][2] += a.z * w.z; acc[2][3] += a.z * w.w;
            acc[3][0] += a.w * w.x; acc[3][1] += a.w * w.y;
            acc[3][2] += a.w * w.z; acc[3][3] += a.w * w.w;
        }
    }
    int r = row0 + tr * 4;
    if (r < n) {
        #pragma unroll
        for (int cj = 0; cj < 4; ++cj) {
            int j = tc * 4 + cj;
            float4 v = make_float4(acc[0][cj], acc[1][cj], acc[2][cj], acc[3][cj]);
            *reinterpret_cast<float4*>(&t1t[(size_t)j * n + r]) = v;
        }
    }
}

// ---------------- tiled GEMM2: relu(bn1(t1)) @ W2 + b2 -> t2t[64][n] --------
__global__ __launch_bounds__(256) void k_gemm2(
        const float* __restrict__ t1t, const float* __restrict__ A1,
        const float* __restrict__ B1, const float* __restrict__ W2,
        const float* __restrict__ b2, float* __restrict__ t2t, int n) {
    __shared__ float xs[HDIM][BM + 4];
    __shared__ float ws[HDIM][HDIM];
    __shared__ float As[HDIM], Bs[HDIM];
    int t = threadIdx.x;
    int row0 = blockIdx.x * BM;
    if (t < HDIM) { As[t] = A1[t]; Bs[t] = B1[t]; }
    __syncthreads();
    int tr = t >> 4, tc = t & 15;
    // stage t1 tile (already [k][row]) with BN1 affine + relu fused
    #pragma unroll
    for (int it = 0; it < 4; ++it) {
        int i = it * 256 + t;
        int kk = i >> 4, q = i & 15;
        float4 v = make_float4(0.f, 0.f, 0.f, 0.f);
        if (row0 + q * 4 < n) {
            v = *reinterpret_cast<const float4*>(&t1t[(size_t)kk * n + row0 + q * 4]);
            float a = As[kk], b = Bs[kk];
            v.x = fmaxf(fmaf(a, v.x, b), 0.f);
            v.y = fmaxf(fmaf(a, v.y, b), 0.f);
            v.z = fmaxf(fmaf(a, v.z, b), 0.f);
            v.w = fmaxf(fmaf(a, v.w, b), 0.f);
        }
        *reinterpret_cast<float4*>(&xs[kk][q * 4]) = v;
    }
    #pragma unroll
    for (int it = 0; it < 4; ++it) {
        int i = it * 256 + t;
        int kk = i >> 4, q = i & 15;
        *reinterpret_cast<float4*>(&ws[kk][q * 4]) =
            *reinterpret_cast<const float4*>(&W2[(size_t)kk * HDIM + q * 4]);
    }
    __syncthreads();
    float acc[4][4];
    float4 bv = *reinterpret_cast<const float4*>(&b2[tc * 4]);
    #pragma unroll
    for (int i = 0; i < 4; ++i) {
        acc[i][0] = bv.x; acc[i][1] = bv.y; acc[i][2] = bv.z; acc[i][3] = bv.w;
    }
    #pragma unroll 8
    for (int kk = 0; kk < HDIM; ++kk) {
        float4 a = *reinterpret_cast<const float4*>(&xs[kk][tr * 4]);
        float4 w = *reinterpret_cast<const float4*>(&ws[kk][tc * 4]);
        acc[0][0] += a.x * w.x; acc[0][1] += a.x * w.y;
        acc[0][2] += a.x * w.z; acc[0][3] += a.x * w.w;
        acc[1][0] += a.y * w.x; acc[1][1] += a.y * w.y;
        acc[1][2] += a.y * w.z; acc[1][3] += a.y * w.w;
        acc[2][0] += a.z * w.x; acc[2][1] += a.z * w.y;
        acc[2][2] += a.z * w.z; acc[2][3] += a.z * w.w;
        acc[3][0] += a.w * w.x; acc[3][1] += a.w * w.y;
        acc[3][2] += a.w * w.z; acc[3][3] += a.w * w.w;
    }
    int r = row0 + tr * 4;
    if (r < n) {
        #pragma unroll
        for (int cj = 0; cj < 4; ++cj) {
            int j = tc * 4 + cj;
            float4 v = make_float4(acc[0][cj], acc[1][cj], acc[2][cj], acc[3][cj]);
            *reinterpret_cast<float4*>(&t2t[(size_t)j * n + r]) = v;
        }
    }
}

// per-feature sum & sumsq over transposed activations [64][n]
__global__ __launch_bounds__(256) void k_stats(
        const float* __restrict__ tt, float* __restrict__ sum,
        float* __restrict__ sq, int n) {
    int feat = blockIdx.x >> 3;
    int chunk = blockIdx.x & 7;
    const float4* p = reinterpret_cast<const float4*>(tt + (size_t)feat * n);
    int n4 = n / 4;
    float s = 0.f, q = 0.f;
    for (int i = chunk * 256 + threadIdx.x; i < n4; i += 8 * 256) {
        float4 v = p[i];
        s += v.x + v.y + v.z + v.w;
        q += v.x * v.x + v.y * v.y + v.z * v.z + v.w * v.w;
    }
    if (chunk == 0 && threadIdx.x < (n & 3)) {
        float v = tt[(size_t)feat * n + (n & ~3) + threadIdx.x];
        s += v; q += v * v;
    }
    #pragma unroll
    for (int off = 32; off; off >>= 1) {
        s += __shfl_down(s, off, 64);
        q += __shfl_down(q, off, 64);
    }
    __shared__ float ls[4], lq[4];
    int wid = threadIdx.x >> 6, lane = threadIdx.x & 63;
    if (lane == 0) { ls[wid] = s; lq[wid] = q; }
    __syncthreads();
    if (threadIdx.x == 0) {
        atomicAdd(&sum[feat], ls[0] + ls[1] + ls[2] + ls[3]);
        atomicAdd(&sq[feat],  lq[0] + lq[1] + lq[2] + lq[3]);
    }
}

__global__ void k_finalize(const float* __restrict__ sum, const float* __restrict__ sq,
        const float* __restrict__ g, const float* __restrict__ be,
        float* __restrict__ A, float* __restrict__ B, int n) {
    int j = threadIdx.x;
    if (j >= HDIM) return;
    float mean = sum[j] / (float)n;
    float var = sq[j] / (float)n - mean * mean;
    float istd = 1.0f / sqrtf(var + 1e-5f);
    A[j] = g[j] * istd;
    B[j] = be[j] - mean * istd * g[j];
}

__global__ __launch_bounds__(256) void k_zflow(
        const float* __restrict__ t2t, const float* __restrict__ A2,
        const float* __restrict__ B2, const float* __restrict__ W3,
        const float* __restrict__ b3, const float* __restrict__ x0,
        const float* __restrict__ ap, const float* __restrict__ bp,
        const float* __restrict__ mu, const float* __restrict__ lv,
        float* __restrict__ out_z, float* __restrict__ out_logq,
        float* __restrict__ out_beta, int n) {
    __shared__ float a_s[NL * NC], b_s[NL * NC], x0_s[NL * NC * DLAT];
    __shared__ float mu_s[NC * DLAT], iv_s[NC * DLAT], slv_s[NC];
    for (int i = threadIdx.x; i < NL * NC; i += 256) {
        float a = softplusf(ap[i]);
        a_s[i] = a;
        b_s[i] = softplusf(bp[i]) - a;
    }
    for (int i = threadIdx.x; i < NL * NC * DLAT; i += 256) x0_s[i] = x0[i];
    for (int i = threadIdx.x; i < NC * DLAT; i += 256) {
        mu_s[i] = mu[i];
        iv_s[i] = expf(-lv[i]);
    }
    if (threadIdx.x < NC) {
        float s = 0.f;
        for (int d = 0; d < DLAT; ++d) s += lv[threadIdx.x * DLAT + d];
        slv_s[threadIdx.x] = s;
    }
    __syncthreads();
    int row = blockIdx.x * 256 + threadIdx.x;
    if (row >= n) return;
    float z[DLAT];
    #pragma unroll
    for (int j = 0; j < DLAT; ++j) z[j] = b3[j];
    for (int k = 0; k < HDIM; ++k) {
        float hv = fmaxf(A2[k] * t2t[(size_t)k * n + row] + B2[k], 0.f);
        const float* w = W3 + k * DLAT;
        #pragma unroll
        for (int j = 0; j < DLAT; ++j) z[j] += hv * w[j];
    }
    #pragma unroll
    for (int j = 0; j < DLAT; ++j) out_z[(size_t)row * DLAT + j] = z[j];

    for (int c = 0; c < NC; ++c) {
        float zz[DLAT];
        #pragma unroll
        for (int d = 0; d < DLAT; ++d) zz[d] = z[d];
        float log_det = 0.f;
        for (int l = NL - 1; l >= 0; --l) {
            float a = a_s[l * NC + c], b = b_s[l * NC + c];
            const float* x0p = &x0_s[(l * NC + c) * DLAT];
            float diff[DLAT];
            float r2 = 0.f;
            #pragma unroll
            for (int d = 0; d < DLAT; ++d) {
                diff[d] = zz[d] - x0p[d];
                r2 += diff[d] * diff[d];
            }
            float r = fmaxf(sqrtf(r2), 1e-8f);
            float h = 1.f / (a + r);
            float bh = b * h;
            #pragma unroll
            for (int d = 0; d < DLAT; ++d) zz[d] += bh * diff[d];
            log_det += (DLAT - 1) * log1pf(bh) + log1pf(bh - bh * h * r);
        }
        float quad = 0.f;
        #pragma unroll
        for (int d = 0; d < DLAT; ++d) {
            float dd = zz[d] - mu_s[c * DLAT + d];
            quad += dd * dd * iv_s[c * DLAT + d];
        }
        float lq = -14.70301653f - 0.5f * slv_s[c] - 0.5f * quad + log_det;
        out_logq[(size_t)row * NC + c] = lq;
        float w = fminf(fmaxf(lq + 20.24819398f, -30.f), 30.f);
        out_beta[(size_t)row * NC + c] = expf(w);
    }
}

// ---------------- pass 1: radix partition edges into NB row-range buckets ----
__global__ __launch_bounds__(256) void k_bucket(
        const int* __restrict__ rows, const int* __restrict__ cols,
        int2* __restrict__ bpairs, int* __restrict__ bcnt, int cap,
        int* __restrict__ cur, int2* __restrict__ ovf, int* __restrict__ ovf_cnt,
        int e, int n, int rpb) {
    __shared__ int lcnt[NB], loff[NB], lcur[NB], gbase[NB], sc[NB];
    __shared__ int2 staged[TILE];
    int t = threadIdx.x;
    int base = blockIdx.x * TILE;
    for (int i = t; i < NB; i += 256) lcnt[i] = 0;
    __syncthreads();
    int er[PERTHREAD], ec[PERTHREAD], eb[PERTHREAD];
    #pragma unroll
    for (int k = 0; k < PERTHREAD; ++k) {
        int i = base + k * 256 + t;
        eb[k] = -1;
        if (i < e) {
            int r = rows[i], c = cols[i];
            if ((unsigned)r < (unsigned)n && (unsigned)c < (unsigned)n) {
                er[k] = r; ec[k] = c;
                int b = (int)((unsigned)r / (unsigned)rpb);
                eb[k] = b;
                atomicAdd(&lcnt[b], 1);
            }
        }
    }
    __syncthreads();
    if (t < NB) sc[t] = lcnt[t];
    __syncthreads();
    for (int off = 1; off < NB; off <<= 1) {
        int v = 0;
        if (t < NB && t >= off) v = sc[t - off];
        __syncthreads();
        if (t < NB) sc[t] += v;
        __syncthreads();
    }
    if (t < NB) { loff[t] = sc[t] - lcnt[t]; lcur[t] = sc[t] - lcnt[t]; }
    __syncthreads();
    #pragma unroll
    for (int k = 0; k < PERTHREAD; ++k) {
        if (eb[k] >= 0) {
            int slot = atomicAdd(&lcur[eb[k]], 1);
            staged[slot] = make_int2(er[k], ec[k]);
        }
    }
    __syncthreads();
    if (t < NB && lcnt[t] > 0) gbase[t] = atomicAdd(&bcnt[t], lcnt[t]);
    __syncthreads();
    int wid = t >> 6, lane = t & 63;
    for (int b = wid; b < NB; b += 4) {
        int cnt = lcnt[b];
        if (!cnt) continue;
        int gb = gbase[b], lo = loff[b];
        for (int k = lane; k < cnt; k += 64) {
            int2 p = staged[lo + k];
            int dst = gb + k;
            if (dst < cap) {
                bpairs[(size_t)b * cap + dst] = p;
            } else {
                int o = atomicAdd(ovf_cnt, 1);
                if (o < OVF_CAP) ovf[o] = p;
                atomicAdd(&cur[p.x], 1);
            }
        }
    }
}

// ---------------- pass 2: per-bucket ELL placement (L2-local writes) --------
__global__ __launch_bounds__(256) void k_build(
        const int2* __restrict__ bpairs, const int* __restrict__ bcnt, int cap,
        int* __restrict__ ecol, int* __restrict__ cur,
        int2* __restrict__ ovf, int* __restrict__ ovf_cnt, int n, int rpb) {
    __shared__ int lcnt[1024];
    int b = blockIdx.x, t = threadIdx.x;
    int row_base = b * rpb;
    int nrows = n - row_base; if (nrows > rpb) nrows = rpb;
    if (nrows <= 0) return;
    for (int i = t; i < nrows; i += 256) lcnt[i] = 0;
    __syncthreads();
    int m = bcnt[b]; if (m > cap) m = cap;
    const int2* bp = bpairs + (size_t)b * cap;
    for (int i = t; i < m; i += 256) {
        int2 p = bp[i];
        int lr = p.x - row_base;
        int j = atomicAdd(&lcnt[lr], 1);
        if (j < ELLW) {
            ecol[(size_t)p.x * ELLW + j] = p.y;
        } else {
            int o = atomicAdd(ovf_cnt, 1);
            if (o < OVF_CAP) ovf[o] = p;
        }
    }
    __syncthreads();
    for (int i = t; i < nrows; i += 256) {
        int c = lcnt[i];
        if (c) cur[row_base + i] += c;
    }
}

__global__ void k_dis(const int* __restrict__ cur, float* __restrict__ dis, int n) {
    int i = blockIdx.x * blockDim.x + threadIdx.x;
    if (i < n) dis[i] = rsqrtf((float)cur[i] + 1.0f);   // +1 = self loop
}

__global__ void k_init_hs(const float* __restrict__ beta, const float* __restrict__ dis,
                          float* __restrict__ hs, int n) {
    int i = blockIdx.x * blockDim.x + threadIdx.x;
    if (i >= n) return;
    float d = dis[i];
    const float4* b = reinterpret_cast<const float4*>(beta + (size_t)i * NC);
    float4* o = reinterpret_cast<float4*>(hs + (size_t)i * NC);
    float4 b0 = b[0], b1 = b[1];
    o[0] = make_float4(d * b0.x, d * b0.y, d * b0.z, d * b0.w);
    o[1] = make_float4(d * b1.x, d * b1.y, d * b1.z, d * b1.w);
}

// ---------------- APPNP gather iteration ----------------
__global__ __launch_bounds__(256) void k_gather(
        const int* __restrict__ cur, const int* __restrict__ ecol,
        const float* __restrict__ hs_in, const float* __restrict__ beta,
        const float* __restrict__ dis, float* __restrict__ hout,
        float* __restrict__ hs_out, const int2* __restrict__ ovf,
        const int* __restrict__ ovf_cnt, int n) {
    int row = (blockIdx.x * blockDim.x + threadIdx.x) >> 3;
    int c = threadIdx.x & 7;
    if (row >= n) return;
    int cnt = cur[row];
    int lim = cnt < ELLW ? cnt : ELLW;
    float d = dis[row];
    const int* ec = ecol + (size_t)row * ELLW;
    float acc = hs_in[row * NC + c];   // self loop
    for (int ep = 0; ep < lim; ++ep) acc += hs_in[ec[ep] * NC + c];
    int m = *ovf_cnt;
    if (m > 0) {   // parachute: expected never taken
        if (m > OVF_CAP) m = OVF_CAP;
        for (int i = 0; i < m; ++i) {
            int2 p = ovf[i];
            if (p.x == row) acc += hs_in[p.y * NC + c];
        }
    }
    float hn = 0.9f * d * acc + 0.1f * beta[row * NC + c];
    hout[row * NC + c] = hn;
    hs_out[row * NC + c] = d * hn;
}

__global__ void k_final(const float* __restrict__ h, float* __restrict__ out_alpha,
        float* __restrict__ out_probs, int n) {
    int i = blockIdx.x * blockDim.x + threadIdx.x;
    if (i >= n) return;
    float a[NC];
    float s = 0.f;
    #pragma unroll
    for (int c = 0; c < NC; ++c) {
        float v = h[(size_t)i * NC + c];
        v = 0.001f + fmaxf(v, 0.f);
        a[c] = v; s += v;
    }
    float inv = 1.f / s;
    #pragma unroll
    for (int c = 0; c < NC; ++c) {
        out_alpha[(size_t)i * NC + c] = a[c];
        out_probs[(size_t)i * NC + c] = a[c] * inv;
    }
}

extern "C" void kernel_launch(void* const* d_in, const int* in_sizes, int n_in,
                              void* d_out, int out_size, void* d_ws, size_t ws_size,
                              hipStream_t stream) {
    const float* x   = (const float*)d_in[0];
    const int*   ei  = (const int*)d_in[1];
    const float* W1  = (const float*)d_in[2];
    const float* b1  = (const float*)d_in[3];
    const float* g1  = (const float*)d_in[4];
    const float* be1 = (const float*)d_in[5];
    const float* W2  = (const float*)d_in[6];
    const float* b2  = (const float*)d_in[7];
    const float* g2  = (const float*)d_in[8];
    const float* be2 = (const float*)d_in[9];
    const float* W3  = (const float*)d_in[10];
    const float* b3  = (const float*)d_in[11];
    const float* x0  = (const float*)d_in[12];
    const float* ap  = (const float*)d_in[13];
    const float* bp  = (const float*)d_in[14];
    const float* mu  = (const float*)d_in[15];
    const float* lv  = (const float*)d_in[16];

    int n = in_sizes[0] / NFEAT_IN;   // 100000
    int e = in_sizes[1] / 2;          // 3200000
    const int* rows = ei;
    const int* cols = ei + e;
    int rpb = (n + NB - 1) / NB;      // 782 rows per bucket
    int cap = (e + e / 16) / NB;      // pairs/bucket (+~10 sigma slack)

    size_t an = (size_t)HDIM * n;
    float* ws  = (float*)d_ws;
    float* t1t = ws;                         // 64n floats; later ecol (64n ints)
    float* t2t = ws + an;                    // 64n floats; later bucket pairs
    int2*  bpairs = (int2*)t2t;              // NB*cap int2
    float* stats = (float*)((char*)t2t + (size_t)NB * cap * sizeof(int2));
    float *sum1 = stats,       *sq1 = stats + 64,  *A1 = stats + 128, *B1 = stats + 192;
    float *sum2 = stats + 256, *sq2 = stats + 320, *A2 = stats + 384, *B2 = stats + 448;
    int*  bcnt    = (int*)(stats + 512);     // NB
    int*  ovf_cnt = bcnt + NB;               // 1 (+pad)
    int2* ovf     = (int2*)(ovf_cnt + 4);    // OVF_CAP int2
    float* hs0 = (float*)bpairs;             // overlays dead bucket region
    float* hs1 = hs0 + (size_t)NC * n;
    int* ecol = (int*)t1t;

    float* out = (float*)d_out;
    float* out_alpha = out;                  // doubles as hout during APPNP
    float* out_probs = out + (size_t)n * NC; // holds cur/dis until k_final
    float* out_z     = out + (size_t)2 * n * NC;
    float* out_beta  = out_z + (size_t)n * DLAT;
    float* out_logq  = out_beta + (size_t)n * NC;

    int*   cur = (int*)out_probs;            // n ints
    float* dis = out_probs + n;              // n floats

    int nb_nodes = (n + 255) / 256;
    int nb_gemm  = (n + BM - 1) / BM;

    hipMemsetAsync(stats, 0, (512 + NB + 4) * sizeof(float), stream);

    // encoder
    k_gemm1<<<nb_gemm, 256, 0, stream>>>(x, W1, b1, t1t, n);
    k_stats<<<HDIM * 8, 256, 0, stream>>>(t1t, sum1, sq1, n);
    k_finalize<<<1, 64, 0, stream>>>(sum1, sq1, g1, be1, A1, B1, n);
    k_gemm2<<<nb_gemm, 256, 0, stream>>>(t1t, A1, B1, W2, b2, t2t, n);
    k_stats<<<HDIM * 8, 256, 0, stream>>>(t2t, sum2, sq2, n);
    k_finalize<<<1, 64, 0, stream>>>(sum2, sq2, g2, be2, A2, B2, n);
    k_zflow<<<nb_nodes, 256, 0, stream>>>(t2t, A2, B2, W3, b3, x0, ap, bp, mu, lv,
                                          out_z, out_logq, out_beta, n);

    // graph build: radix partition then per-bucket ELL placement
    hipMemsetAsync(cur, 0, (size_t)n * sizeof(int), stream);
    int nt_bucket = (e + TILE - 1) / TILE;
    k_bucket<<<nt_bucket, 256, 0, stream>>>(rows, cols, bpairs, bcnt, cap,
                                            cur, ovf, ovf_cnt, e, n, rpb);
    k_build<<<NB, 256, 0, stream>>>(bpairs, bcnt, cap, ecol, cur, ovf, ovf_cnt, n, rpb);
    k_dis<<<nb_nodes, 256, 0, stream>>>(cur, dis, n);
    k_init_hs<<<nb_nodes, 256, 0, stream>>>(out_beta, dis, hs0, n);

    // APPNP: 10 gather rounds, ping-pong hs0/hs1; hout lives in out_alpha
    int nb_gather = (int)(((size_t)n * 8 + 255) / 256);
    for (int it = 0; it < KPROP; ++it) {
        const float* hin = (it & 1) ? hs1 : hs0;
        float* hso = (it & 1) ? hs0 : hs1;
        k_gather<<<nb_gather, 256, 0, stream>>>(cur, ecol, hin, out_beta, dis,
                                                out_alpha, hso, ovf, ovf_cnt, n);
    }
    k_final<<<nb_nodes, 256, 0, stream>>>(out_alpha, out_alpha, out_probs, n);
}

// Round 6
// 528.110 us; speedup vs baseline: 25.3172x; 1.4654x over previous
//
#include <hip/hip_runtime.h>

#define NFEAT_IN 256
#define HDIM 64
#define DLAT 16
#define NC 8
#define NL 10
#define KPROP 10
#define ELLW 64
#define OVF_CAP 8192
#define NB 128          // row-range buckets
#define PERTHREAD 16
#define TILE (256 * PERTHREAD)
#define BM 64           // GEMM row tile
#define BKT 64          // GEMM k tile

__device__ __forceinline__ float softplusf(float x) {
    return (x > 20.f) ? x : log1pf(expf(x));
}

// ---------------- tiled GEMM1: x[n][256] @ W1[256][64] + b1 -> t1t[64][n] ----
__global__ __launch_bounds__(256) void k_gemm1(
        const float* __restrict__ x, const float* __restrict__ W1,
        const float* __restrict__ b1, float* __restrict__ t1t, int n) {
    __shared__ float xs[BKT][BM + 4];   // [k][row], +4 keeps 16B alignment
    __shared__ float ws[BKT][HDIM];     // [k][j]
    int t = threadIdx.x;
    int row0 = blockIdx.x * BM;
    int tr = t >> 4, tc = t & 15;       // 16x16 thread grid; 4x4 micro-tile
    float acc[4][4];
    float4 bv = *reinterpret_cast<const float4*>(&b1[tc * 4]);
    #pragma unroll
    for (int i = 0; i < 4; ++i) {
        acc[i][0] = bv.x; acc[i][1] = bv.y; acc[i][2] = bv.z; acc[i][3] = bv.w;
    }
    for (int k0 = 0; k0 < NFEAT_IN; k0 += BKT) {
        __syncthreads();
        #pragma unroll
        for (int it = 0; it < 4; ++it) {
            int i = it * 256 + t;
            int row = i >> 4, q = i & 15;
            int grow = row0 + row;
            float4 v = make_float4(0.f, 0.f, 0.f, 0.f);
            if (grow < n)
                v = *reinterpret_cast<const float4*>(
                        &x[(size_t)grow * NFEAT_IN + k0 + q * 4]);
            xs[q * 4 + 0][row] = v.x;
            xs[q * 4 + 1][row] = v.y;
            xs[q * 4 + 2][row] = v.z;
            xs[q * 4 + 3][row] = v.w;
        }
        #pragma unroll
        for (int it = 0; it < 4; ++it) {
            int i = it * 256 + t;
            int kk = i >> 4, q = i & 15;
            *reinterpret_cast<float4*>(&ws[kk][q * 4]) =
                *reinterpret_cast<const float4*>(&W1[(size_t)(k0 + kk) * HDIM + q * 4]);
        }
        __syncthreads();
        #pragma unroll 8
        for (int kk = 0; kk < BKT; ++kk) {
            float4 a = *reinterpret_cast<const float4*>(&xs[kk][tr * 4]);
            float4 w = *reinterpret_cast<const float4*>(&ws[kk][tc * 4]);
            acc[0][0] += a.x * w.x; acc[0][1] += a.x * w.y;
            acc[0][2] += a.x * w.z; acc[0][3] += a.x * w.w;
            acc[1][0] += a.y * w.x; acc[1][1] += a.y * w.y;
            acc[1][2] += a.y * w.z; acc[1][3] += a.y * w.w;
            acc[2][0] += a.z * w.x; acc[2][1] += a.z * w.y;
            acc[2][2] += a.z * w.z; acc[2][3] += a.z * w.w;
            acc[3][0] += a.w * w.x; acc[3][1] += a.w * w.y;
            acc[3][2] += a.w * w.z; acc[3][3] += a.w * w.w;
        }
    }
    int r = row0 + tr * 4;
    if (r < n) {
        #pragma unroll
        for (int cj = 0; cj < 4; ++cj) {
            int j = tc * 4 + cj;
            float4 v = make_float4(acc[0][cj], acc[1][cj], acc[2][cj], acc[3][cj]);
            *reinterpret_cast<float4*>(&t1t[(size_t)j * n + r]) = v;
        }
    }
}

// ---------------- tiled GEMM2: relu(bn1(t1)) @ W2 + b2 -> t2t[64][n] --------
__global__ __launch_bounds__(256) void k_gemm2(
        const float* __restrict__ t1t, const float* __restrict__ A1,
        const float* __restrict__ B1, const float* __restrict__ W2,
        const float* __restrict__ b2, float* __restrict__ t2t, int n) {
    __shared__ float xs[HDIM][BM + 4];
    __shared__ float ws[HDIM][HDIM];
    __shared__ float As[HDIM], Bs[HDIM];
    int t = threadIdx.x;
    int row0 = blockIdx.x * BM;
    if (t < HDIM) { As[t] = A1[t]; Bs[t] = B1[t]; }
    __syncthreads();
    int tr = t >> 4, tc = t & 15;
    #pragma unroll
    for (int it = 0; it < 4; ++it) {
        int i = it * 256 + t;
        int kk = i >> 4, q = i & 15;
        float4 v = make_float4(0.f, 0.f, 0.f, 0.f);
        if (row0 + q * 4 < n) {
            v = *reinterpret_cast<const float4*>(&t1t[(size_t)kk * n + row0 + q * 4]);
            float a = As[kk], b = Bs[kk];
            v.x = fmaxf(fmaf(a, v.x, b), 0.f);
            v.y = fmaxf(fmaf(a, v.y, b), 0.f);
            v.z = fmaxf(fmaf(a, v.z, b), 0.f);
            v.w = fmaxf(fmaf(a, v.w, b), 0.f);
        }
        *reinterpret_cast<float4*>(&xs[kk][q * 4]) = v;
    }
    #pragma unroll
    for (int it = 0; it < 4; ++it) {
        int i = it * 256 + t;
        int kk = i >> 4, q = i & 15;
        *reinterpret_cast<float4*>(&ws[kk][q * 4]) =
            *reinterpret_cast<const float4*>(&W2[(size_t)kk * HDIM + q * 4]);
    }
    __syncthreads();
    float acc[4][4];
    float4 bv = *reinterpret_cast<const float4*>(&b2[tc * 4]);
    #pragma unroll
    for (int i = 0; i < 4; ++i) {
        acc[i][0] = bv.x; acc[i][1] = bv.y; acc[i][2] = bv.z; acc[i][3] = bv.w;
    }
    #pragma unroll 8
    for (int kk = 0; kk < HDIM; ++kk) {
        float4 a = *reinterpret_cast<const float4*>(&xs[kk][tr * 4]);
        float4 w = *reinterpret_cast<const float4*>(&ws[kk][tc * 4]);
        acc[0][0] += a.x * w.x; acc[0][1] += a.x * w.y;
        acc[0][2] += a.x * w.z; acc[0][3] += a.x * w.w;
        acc[1][0] += a.y * w.x; acc[1][1] += a.y * w.y;
        acc[1][2] += a.y * w.z; acc[1][3] += a.y * w.w;
        acc[2][0] += a.z * w.x; acc[2][1] += a.z * w.y;
        acc[2][2] += a.z * w.z; acc[2][3] += a.z * w.w;
        acc[3][0] += a.w * w.x; acc[3][1] += a.w * w.y;
        acc[3][2] += a.w * w.z; acc[3][3] += a.w * w.w;
    }
    int r = row0 + tr * 4;
    if (r < n) {
        #pragma unroll
        for (int cj = 0; cj < 4; ++cj) {
            int j = tc * 4 + cj;
            float4 v = make_float4(acc[0][cj], acc[1][cj], acc[2][cj], acc[3][cj]);
            *reinterpret_cast<float4*>(&t2t[(size_t)j * n + r]) = v;
        }
    }
}

// per-feature sum & sumsq over transposed activations [64][n]
__global__ __launch_bounds__(256) void k_stats(
        const float* __restrict__ tt, float* __restrict__ sum,
        float* __restrict__ sq, int n) {
    int feat = blockIdx.x >> 3;
    int chunk = blockIdx.x & 7;
    const float4* p = reinterpret_cast<const float4*>(tt + (size_t)feat * n);
    int n4 = n / 4;
    float s = 0.f, q = 0.f;
    for (int i = chunk * 256 + threadIdx.x; i < n4; i += 8 * 256) {
        float4 v = p[i];
        s += v.x + v.y + v.z + v.w;
        q += v.x * v.x + v.y * v.y + v.z * v.z + v.w * v.w;
    }
    if (chunk == 0 && threadIdx.x < (n & 3)) {
        float v = tt[(size_t)feat * n + (n & ~3) + threadIdx.x];
        s += v; q += v * v;
    }
    #pragma unroll
    for (int off = 32; off; off >>= 1) {
        s += __shfl_down(s, off, 64);
        q += __shfl_down(q, off, 64);
    }
    __shared__ float ls[4], lq[4];
    int wid = threadIdx.x >> 6, lane = threadIdx.x & 63;
    if (lane == 0) { ls[wid] = s; lq[wid] = q; }
    __syncthreads();
    if (threadIdx.x == 0) {
        atomicAdd(&sum[feat], ls[0] + ls[1] + ls[2] + ls[3]);
        atomicAdd(&sq[feat],  lq[0] + lq[1] + lq[2] + lq[3]);
    }
}

__global__ void k_finalize(const float* __restrict__ sum, const float* __restrict__ sq,
        const float* __restrict__ g, const float* __restrict__ be,
        float* __restrict__ A, float* __restrict__ B, int n) {
    int j = threadIdx.x;
    if (j >= HDIM) return;
    float mean = sum[j] / (float)n;
    float var = sq[j] / (float)n - mean * mean;
    float istd = 1.0f / sqrtf(var + 1e-5f);
    A[j] = g[j] * istd;
    B[j] = be[j] - mean * istd * g[j];
}

// ---------------- z = relu(bn2(t2)) @ W3 + b3 (GEMV per node) ----------------
__global__ __launch_bounds__(256) void k_zlin(
        const float* __restrict__ t2t, const float* __restrict__ A2,
        const float* __restrict__ B2, const float* __restrict__ W3,
        const float* __restrict__ b3, float* __restrict__ out_z, int n) {
    __shared__ float As[HDIM], Bs[HDIM], Ws[HDIM * DLAT];
    int t = threadIdx.x;
    if (t < HDIM) { As[t] = A2[t]; Bs[t] = B2[t]; }
    for (int i = t; i < HDIM * DLAT; i += 256) Ws[i] = W3[i];
    __syncthreads();
    int row = blockIdx.x * 256 + t;
    if (row >= n) return;
    float z[DLAT];
    #pragma unroll
    for (int j = 0; j < DLAT; ++j) z[j] = b3[j];
    for (int k = 0; k < HDIM; ++k) {
        float hv = fmaxf(fmaf(As[k], t2t[(size_t)k * n + row], Bs[k]), 0.f);
        const float* w = &Ws[k * DLAT];
        #pragma unroll
        for (int j = 0; j < DLAT; ++j) z[j] = fmaf(hv, w[j], z[j]);
    }
    float4* zp = reinterpret_cast<float4*>(&out_z[(size_t)row * DLAT]);
    zp[0] = make_float4(z[0], z[1], z[2], z[3]);
    zp[1] = make_float4(z[4], z[5], z[6], z[7]);
    zp[2] = make_float4(z[8], z[9], z[10], z[11]);
    zp[3] = make_float4(z[12], z[13], z[14], z[15]);
}

// ---------------- radial flow: one thread per (node, class) ----------------
__global__ __launch_bounds__(256) void k_flow(
        const float* __restrict__ zbuf, const float* __restrict__ x0,
        const float* __restrict__ ap, const float* __restrict__ bp,
        const float* __restrict__ mu, const float* __restrict__ lv,
        float* __restrict__ out_logq, float* __restrict__ out_beta, int n) {
    __shared__ float a_s[NL * NC], b_s[NL * NC];
    __shared__ float x0_s[NL * NC][DLAT + 1];   // pad -> no 4-way bank conflict
    __shared__ float mu_s[NC][DLAT + 1], iv_s[NC][DLAT + 1], slv_s[NC];
    int t = threadIdx.x;
    for (int i = t; i < NL * NC; i += 256) {
        float a = softplusf(ap[i]);
        a_s[i] = a;
        b_s[i] = softplusf(bp[i]) - a;
    }
    for (int i = t; i < NL * NC * DLAT; i += 256) x0_s[i >> 4][i & 15] = x0[i];
    for (int i = t; i < NC * DLAT; i += 256) {
        mu_s[i >> 4][i & 15] = mu[i];
        iv_s[i >> 4][i & 15] = __expf(-lv[i]);
    }
    if (t < NC) {
        float s = 0.f;
        for (int d = 0; d < DLAT; ++d) s += lv[t * DLAT + d];
        slv_s[t] = s;
    }
    __syncthreads();
    int gid = blockIdx.x * 256 + t;
    int row = gid >> 3, c = gid & 7;
    if (row >= n) return;
    float zz[DLAT];
    const float4* zp = reinterpret_cast<const float4*>(&zbuf[(size_t)row * DLAT]);
    float4 z0 = zp[0], z1 = zp[1], z2 = zp[2], z3 = zp[3];
    zz[0] = z0.x; zz[1] = z0.y; zz[2] = z0.z; zz[3] = z0.w;
    zz[4] = z1.x; zz[5] = z1.y; zz[6] = z1.z; zz[7] = z1.w;
    zz[8] = z2.x; zz[9] = z2.y; zz[10] = z2.z; zz[11] = z2.w;
    zz[12] = z3.x; zz[13] = z3.y; zz[14] = z3.z; zz[15] = z3.w;

    float log_det = 0.f;
    #pragma unroll
    for (int l = NL - 1; l >= 0; --l) {
        int idx = l * NC + c;
        float a = a_s[idx], b = b_s[idx];
        const float* x0p = x0_s[idx];
        float diff[DLAT];
        float r2 = 0.f;
        #pragma unroll
        for (int d = 0; d < DLAT; ++d) {
            diff[d] = zz[d] - x0p[d];
            r2 = fmaf(diff[d], diff[d], r2);
        }
        float r = fmaxf(sqrtf(r2), 1e-8f);
        float h = 1.f / (a + r);
        float bh = b * h;
        #pragma unroll
        for (int d = 0; d < DLAT; ++d) zz[d] = fmaf(bh, diff[d], zz[d]);
        log_det += (DLAT - 1) * __logf(1.f + bh) + __logf(1.f + bh - bh * h * r);
    }
    float quad = 0.f;
    #pragma unroll
    for (int d = 0; d < DLAT; ++d) {
        float dd = zz[d] - mu_s[c][d];
        quad = fmaf(dd * dd, iv_s[c][d], quad);
    }
    float lq = -14.70301653f - 0.5f * slv_s[c] - 0.5f * quad + log_det;
    out_logq[gid] = lq;
    float w = fminf(fmaxf(lq + 20.24819398f, -30.f), 30.f);
    out_beta[gid] = __expf(w);
}

// ---------------- pass 1: radix partition edges into NB row-range buckets ----
__global__ __launch_bounds__(256) void k_bucket(
        const int* __restrict__ rows, const int* __restrict__ cols,
        int2* __restrict__ bpairs, int* __restrict__ bcnt, int cap,
        int* __restrict__ cur, int2* __restrict__ ovf, int* __restrict__ ovf_cnt,
        int e, int n, int rpb) {
    __shared__ int lcnt[NB], loff[NB], lcur[NB], gbase[NB], sc[NB];
    __shared__ int2 staged[TILE];
    int t = threadIdx.x;
    int base = blockIdx.x * TILE;
    for (int i = t; i < NB; i += 256) lcnt[i] = 0;
    __syncthreads();
    int er[PERTHREAD], ec[PERTHREAD], eb[PERTHREAD];
    #pragma unroll
    for (int k = 0; k < PERTHREAD; ++k) {
        int i = base + k * 256 + t;
        eb[k] = -1;
        if (i < e) {
            int r = rows[i], c = cols[i];
            if ((unsigned)r < (unsigned)n && (unsigned)c < (unsigned)n) {
                er[k] = r; ec[k] = c;
                int b = (int)((unsigned)r / (unsigned)rpb);
                eb[k] = b;
                atomicAdd(&lcnt[b], 1);
            }
        }
    }
    __syncthreads();
    if (t < NB) sc[t] = lcnt[t];
    __syncthreads();
    for (int off = 1; off < NB; off <<= 1) {
        int v = 0;
        if (t < NB && t >= off) v = sc[t - off];
        __syncthreads();
        if (t < NB) sc[t] += v;
        __syncthreads();
    }
    if (t < NB) { loff[t] = sc[t] - lcnt[t]; lcur[t] = sc[t] - lcnt[t]; }
    __syncthreads();
    #pragma unroll
    for (int k = 0; k < PERTHREAD; ++k) {
        if (eb[k] >= 0) {
            int slot = atomicAdd(&lcur[eb[k]], 1);
            staged[slot] = make_int2(er[k], ec[k]);
        }
    }
    __syncthreads();
    if (t < NB && lcnt[t] > 0) gbase[t] = atomicAdd(&bcnt[t], lcnt[t]);
    __syncthreads();
    int wid = t >> 6, lane = t & 63;
    for (int b = wid; b < NB; b += 4) {
        int cnt = lcnt[b];
        if (!cnt) continue;
        int gb = gbase[b], lo = loff[b];
        for (int k = lane; k < cnt; k += 64) {
            int2 p = staged[lo + k];
            int dst = gb + k;
            if (dst < cap) {
                bpairs[(size_t)b * cap + dst] = p;
            } else {
                int o = atomicAdd(ovf_cnt, 1);
                if (o < OVF_CAP) ovf[o] = p;
                atomicAdd(&cur[p.x], 1);
            }
        }
    }
}

// ---------------- pass 2: per-bucket ELL placement (L2-local writes) --------
__global__ __launch_bounds__(256) void k_build(
        const int2* __restrict__ bpairs, const int* __restrict__ bcnt, int cap,
        int* __restrict__ ecol, int* __restrict__ cur,
        int2* __restrict__ ovf, int* __restrict__ ovf_cnt, int n, int rpb) {
    __shared__ int lcnt[1024];
    int b = blockIdx.x, t = threadIdx.x;
    int row_base = b * rpb;
    int nrows = n - row_base; if (nrows > rpb) nrows = rpb;
    if (nrows <= 0) return;
    for (int i = t; i < nrows; i += 256) lcnt[i] = 0;
    __syncthreads();
    int m = bcnt[b]; if (m > cap) m = cap;
    const int2* bp = bpairs + (size_t)b * cap;
    for (int i = t; i < m; i += 256) {
        int2 p = bp[i];
        int lr = p.x - row_base;
        int j = atomicAdd(&lcnt[lr], 1);
        if (j < ELLW) {
            ecol[(size_t)p.x * ELLW + j] = p.y;
        } else {
            int o = atomicAdd(ovf_cnt, 1);
            if (o < OVF_CAP) ovf[o] = p;
        }
    }
    __syncthreads();
    for (int i = t; i < nrows; i += 256) {
        int c = lcnt[i];
        if (c) cur[row_base + i] += c;
    }
}

__global__ void k_dis(const int* __restrict__ cur, float* __restrict__ dis, int n) {
    int i = blockIdx.x * blockDim.x + threadIdx.x;
    if (i < n) dis[i] = rsqrtf((float)cur[i] + 1.0f);   // +1 = self loop
}

__global__ void k_init_hs(const float* __restrict__ beta, const float* __restrict__ dis,
                          float* __restrict__ hs, int n) {
    int i = blockIdx.x * blockDim.x + threadIdx.x;
    if (i >= n) return;
    float d = dis[i];
    const float4* b = reinterpret_cast<const float4*>(beta + (size_t)i * NC);
    float4* o = reinterpret_cast<float4*>(hs + (size_t)i * NC);
    float4 b0 = b[0], b1 = b[1];
    o[0] = make_float4(d * b0.x, d * b0.y, d * b0.z, d * b0.w);
    o[1] = make_float4(d * b1.x, d * b1.y, d * b1.z, d * b1.w);
}

// ---------------- APPNP gather iteration ----------------
// 4-wide unrolled edge walk: independent gathers in flight for MLP.
__global__ __launch_bounds__(256) void k_gather(
        const int* __restrict__ cur, const int* __restrict__ ecol,
        const float* __restrict__ hs_in, const float* __restrict__ beta,
        const float* __restrict__ dis, float* __restrict__ hout,
        float* __restrict__ hs_out, const int2* __restrict__ ovf,
        const int* __restrict__ ovf_cnt, int n) {
    int row = (blockIdx.x * blockDim.x + threadIdx.x) >> 3;
    int c = threadIdx.x & 7;
    if (row >= n) return;
    int cnt = cur[row];
    int lim = cnt < ELLW ? cnt : ELLW;
    float d = dis[row];
    const int* ec = ecol + (size_t)row * ELLW;
    const int4* ec4 = reinterpret_cast<const int4*>(ec);
    float acc = hs_in[row * NC + c];   // self loop
    float a0 = 0.f, a1 = 0.f, a2 = 0.f, a3 = 0.f;
    int lim4 = lim & ~3;
    for (int ep = 0; ep < lim4; ep += 4) {
        int4 e4 = ec4[ep >> 2];
        a0 += hs_in[e4.x * NC + c];
        a1 += hs_in[e4.y * NC + c];
        a2 += hs_in[e4.z * NC + c];
        a3 += hs_in[e4.w * NC + c];
    }
    for (int ep = lim4; ep < lim; ++ep) acc += hs_in[ec[ep] * NC + c];
    acc += (a0 + a1) + (a2 + a3);
    int m = *ovf_cnt;
    if (m > 0) {   // parachute: expected never taken
        if (m > OVF_CAP) m = OVF_CAP;
        for (int i = 0; i < m; ++i) {
            int2 p = ovf[i];
            if (p.x == row) acc += hs_in[p.y * NC + c];
        }
    }
    float hn = 0.9f * d * acc + 0.1f * beta[row * NC + c];
    hout[row * NC + c] = hn;
    hs_out[row * NC + c] = d * hn;
}

__global__ void k_final(const float* __restrict__ h, float* __restrict__ out_alpha,
        float* __restrict__ out_probs, int n) {
    int i = blockIdx.x * blockDim.x + threadIdx.x;
    if (i >= n) return;
    float a[NC];
    float s = 0.f;
    #pragma unroll
    for (int c = 0; c < NC; ++c) {
        float v = h[(size_t)i * NC + c];
        v = 0.001f + fmaxf(v, 0.f);
        a[c] = v; s += v;
    }
    float inv = 1.f / s;
    #pragma unroll
    for (int c = 0; c < NC; ++c) {
        out_alpha[(size_t)i * NC + c] = a[c];
        out_probs[(size_t)i * NC + c] = a[c] * inv;
    }
}

extern "C" void kernel_launch(void* const* d_in, const int* in_sizes, int n_in,
                              void* d_out, int out_size, void* d_ws, size_t ws_size,
                              hipStream_t stream) {
    const float* x   = (const float*)d_in[0];
    const int*   ei  = (const int*)d_in[1];
    const float* W1  = (const float*)d_in[2];
    const float* b1  = (const float*)d_in[3];
    const float* g1  = (const float*)d_in[4];
    const float* be1 = (const float*)d_in[5];
    const float* W2  = (const float*)d_in[6];
    const float* b2  = (const float*)d_in[7];
    const float* g2  = (const float*)d_in[8];
    const float* be2 = (const float*)d_in[9];
    const float* W3  = (const float*)d_in[10];
    const float* b3  = (const float*)d_in[11];
    const float* x0  = (const float*)d_in[12];
    const float* ap  = (const float*)d_in[13];
    const float* bp  = (const float*)d_in[14];
    const float* mu  = (const float*)d_in[15];
    const float* lv  = (const float*)d_in[16];

    int n = in_sizes[0] / NFEAT_IN;   // 100000
    int e = in_sizes[1] / 2;          // 3200000
    const int* rows = ei;
    const int* cols = ei + e;
    int rpb = (n + NB - 1) / NB;      // 782 rows per bucket
    int cap = (e + e / 16) / NB;      // pairs/bucket (+~10 sigma slack)

    size_t an = (size_t)HDIM * n;
    float* ws  = (float*)d_ws;
    float* t1t = ws;                         // 64n floats; later ecol (64n ints)
    float* t2t = ws + an;                    // 64n floats; later bucket pairs
    int2*  bpairs = (int2*)t2t;              // NB*cap int2
    float* stats = (float*)((char*)t2t + (size_t)NB * cap * sizeof(int2));
    float *sum1 = stats,       *sq1 = stats + 64,  *A1 = stats + 128, *B1 = stats + 192;
    float *sum2 = stats + 256, *sq2 = stats + 320, *A2 = stats + 384, *B2 = stats + 448;
    int*  bcnt    = (int*)(stats + 512);     // NB
    int*  ovf_cnt = bcnt + NB;               // 1 (+pad)
    int2* ovf     = (int2*)(ovf_cnt + 4);    // OVF_CAP int2
    float* hs0 = (float*)bpairs;             // overlays dead bucket region
    float* hs1 = hs0 + (size_t)NC * n;
    int* ecol = (int*)t1t;

    float* out = (float*)d_out;
    float* out_alpha = out;                  // doubles as hout during APPNP
    float* out_probs = out + (size_t)n * NC; // holds cur/dis until k_final
    float* out_z     = out + (size_t)2 * n * NC;
    float* out_beta  = out_z + (size_t)n * DLAT;
    float* out_logq  = out_beta + (size_t)n * NC;

    int*   cur = (int*)out_probs;            // n ints
    float* dis = out_probs + n;              // n floats

    int nb_nodes = (n + 255) / 256;
    int nb_gemm  = (n + BM - 1) / BM;
    int nb_nc    = (int)(((size_t)n * NC + 255) / 256);

    hipMemsetAsync(stats, 0, (512 + NB + 4) * sizeof(float), stream);

    // encoder
    k_gemm1<<<nb_gemm, 256, 0, stream>>>(x, W1, b1, t1t, n);
    k_stats<<<HDIM * 8, 256, 0, stream>>>(t1t, sum1, sq1, n);
    k_finalize<<<1, 64, 0, stream>>>(sum1, sq1, g1, be1, A1, B1, n);
    k_gemm2<<<nb_gemm, 256, 0, stream>>>(t1t, A1, B1, W2, b2, t2t, n);
    k_stats<<<HDIM * 8, 256, 0, stream>>>(t2t, sum2, sq2, n);
    k_finalize<<<1, 64, 0, stream>>>(sum2, sq2, g2, be2, A2, B2, n);
    k_zlin<<<nb_nodes, 256, 0, stream>>>(t2t, A2, B2, W3, b3, out_z, n);
    k_flow<<<nb_nc, 256, 0, stream>>>(out_z, x0, ap, bp, mu, lv,
                                      out_logq, out_beta, n);

    // graph build: radix partition then per-bucket ELL placement
    hipMemsetAsync(cur, 0, (size_t)n * sizeof(int), stream);
    int nt_bucket = (e + TILE - 1) / TILE;
    k_bucket<<<nt_bucket, 256, 0, stream>>>(rows, cols, bpairs, bcnt, cap,
                                            cur, ovf, ovf_cnt, e, n, rpb);
    k_build<<<NB, 256, 0, stream>>>(bpairs, bcnt, cap, ecol, cur, ovf, ovf_cnt, n, rpb);
    k_dis<<<nb_nodes, 256, 0, stream>>>(cur, dis, n);
    k_init_hs<<<nb_nodes, 256, 0, stream>>>(out_beta, dis, hs0, n);

    // APPNP: 10 gather rounds, ping-pong hs0/hs1; hout lives in out_alpha
    for (int it = 0; it < KPROP; ++it) {
        const float* hin = (it & 1) ? hs1 : hs0;
        float* hso = (it & 1) ? hs0 : hs1;
        k_gather<<<nb_nc, 256, 0, stream>>>(cur, ecol, hin, out_beta, dis,
                                            out_alpha, hso, ovf, ovf_cnt, n);
    }
    k_final<<<nb_nodes, 256, 0, stream>>>(out_alpha, out_alpha, out_probs, n);
}

// Round 7
// 518.932 us; speedup vs baseline: 25.7649x; 1.0177x over previous
//
#include <hip/hip_runtime.h>

#define NFEAT_IN 256
#define HDIM 64
#define DLAT 16
#define NC 8
#define NL 10
#define KPROP 10
#define ELLW 64
#define OVF_CAP 8192
#define NB 128          // row-range buckets
#define PERTHREAD 16
#define TILE (256 * PERTHREAD)
#define BM 64           // GEMM row tile
#define BK1 32          // GEMM k tile

__device__ __forceinline__ float softplusf(float x) {
    return (x > 20.f) ? x : log1pf(expf(x));
}

// ---------------- GEMM1: x[n][256] @ W1[256][64] + b1 -> t1t[64][n] ----------
// xs row-major [row][k] so staging is float4->float4 (no transpose, no conflicts).
__global__ __launch_bounds__(256) void k_gemm1(
        const float* __restrict__ x, const float* __restrict__ W1,
        const float* __restrict__ b1, float* __restrict__ t1t, int n) {
    __shared__ float xs[BM][BK1 + 4];   // 64 x 36 = 9.2 KB
    __shared__ float ws[BK1][HDIM];     // 32 x 64 = 8 KB
    int t = threadIdx.x;
    int row0 = blockIdx.x * BM;
    int tr = t >> 4, tc = t & 15;       // 16x16 thread grid; 4x4 micro-tile
    float acc[4][4];
    float4 bv = *reinterpret_cast<const float4*>(&b1[tc * 4]);
    #pragma unroll
    for (int i = 0; i < 4; ++i) {
        acc[i][0] = bv.x; acc[i][1] = bv.y; acc[i][2] = bv.z; acc[i][3] = bv.w;
    }
    for (int k0 = 0; k0 < NFEAT_IN; k0 += BK1) {
        __syncthreads();
        // stage x tile: 64 rows x 32 k = 512 float4, 2 iters, conflict-free b128
        #pragma unroll
        for (int it = 0; it < 2; ++it) {
            int i = it * 256 + t;
            int row = i >> 3, q = i & 7;
            int grow = row0 + row;
            float4 v = make_float4(0.f, 0.f, 0.f, 0.f);
            if (grow < n)
                v = *reinterpret_cast<const float4*>(
                        &x[(size_t)grow * NFEAT_IN + k0 + q * 4]);
            *reinterpret_cast<float4*>(&xs[row][q * 4]) = v;
        }
        // stage W tile: 32 k x 64 j
        #pragma unroll
        for (int it = 0; it < 2; ++it) {
            int i = it * 256 + t;
            int kk = i >> 4, q = i & 15;
            *reinterpret_cast<float4*>(&ws[kk][q * 4]) =
                *reinterpret_cast<const float4*>(&W1[(size_t)(k0 + kk) * HDIM + q * 4]);
        }
        __syncthreads();
        #pragma unroll 8
        for (int kk = 0; kk < BK1; ++kk) {
            float a0 = xs[tr * 4 + 0][kk];
            float a1 = xs[tr * 4 + 1][kk];
            float a2 = xs[tr * 4 + 2][kk];
            float a3 = xs[tr * 4 + 3][kk];
            float4 w = *reinterpret_cast<const float4*>(&ws[kk][tc * 4]);
            acc[0][0] = fmaf(a0, w.x, acc[0][0]); acc[0][1] = fmaf(a0, w.y, acc[0][1]);
            acc[0][2] = fmaf(a0, w.z, acc[0][2]); acc[0][3] = fmaf(a0, w.w, acc[0][3]);
            acc[1][0] = fmaf(a1, w.x, acc[1][0]); acc[1][1] = fmaf(a1, w.y, acc[1][1]);
            acc[1][2] = fmaf(a1, w.z, acc[1][2]); acc[1][3] = fmaf(a1, w.w, acc[1][3]);
            acc[2][0] = fmaf(a2, w.x, acc[2][0]); acc[2][1] = fmaf(a2, w.y, acc[2][1]);
            acc[2][2] = fmaf(a2, w.z, acc[2][2]); acc[2][3] = fmaf(a2, w.w, acc[2][3]);
            acc[3][0] = fmaf(a3, w.x, acc[3][0]); acc[3][1] = fmaf(a3, w.y, acc[3][1]);
            acc[3][2] = fmaf(a3, w.z, acc[3][2]); acc[3][3] = fmaf(a3, w.w, acc[3][3]);
        }
    }
    int r = row0 + tr * 4;
    if (r < n) {
        #pragma unroll
        for (int cj = 0; cj < 4; ++cj) {
            int j = tc * 4 + cj;
            float4 v = make_float4(acc[0][cj], acc[1][cj], acc[2][cj], acc[3][cj]);
            *reinterpret_cast<float4*>(&t1t[(size_t)j * n + r]) = v;
        }
    }
}

// ---------------- GEMM2: relu(bn1(t1)) @ W2 + b2 -> t2t[64][n] --------------
// t1t is [k][n]: xs [kk][row] stages float4->float4 (no transpose), K split 2x32.
__global__ __launch_bounds__(256) void k_gemm2(
        const float* __restrict__ t1t, const float* __restrict__ A1,
        const float* __restrict__ B1, const float* __restrict__ W2,
        const float* __restrict__ b2, float* __restrict__ t2t, int n) {
    __shared__ float xs[BK1][BM + 4];   // 32 x 68
    __shared__ float ws[BK1][HDIM];     // 32 x 64
    __shared__ float As[HDIM], Bs[HDIM];
    int t = threadIdx.x;
    int row0 = blockIdx.x * BM;
    if (t < HDIM) { As[t] = A1[t]; Bs[t] = B1[t]; }
    int tr = t >> 4, tc = t & 15;
    float acc[4][4];
    float4 bv = *reinterpret_cast<const float4*>(&b2[tc * 4]);
    #pragma unroll
    for (int i = 0; i < 4; ++i) {
        acc[i][0] = bv.x; acc[i][1] = bv.y; acc[i][2] = bv.z; acc[i][3] = bv.w;
    }
    for (int k0 = 0; k0 < HDIM; k0 += BK1) {
        __syncthreads();
        #pragma unroll
        for (int it = 0; it < 2; ++it) {
            int i = it * 256 + t;
            int kk = i >> 4, q = i & 15;
            float4 v = make_float4(0.f, 0.f, 0.f, 0.f);
            if (row0 + q * 4 < n) {
                v = *reinterpret_cast<const float4*>(
                        &t1t[(size_t)(k0 + kk) * n + row0 + q * 4]);
                float a = As[k0 + kk], b = Bs[k0 + kk];
                v.x = fmaxf(fmaf(a, v.x, b), 0.f);
                v.y = fmaxf(fmaf(a, v.y, b), 0.f);
                v.z = fmaxf(fmaf(a, v.z, b), 0.f);
                v.w = fmaxf(fmaf(a, v.w, b), 0.f);
            }
            *reinterpret_cast<float4*>(&xs[kk][q * 4]) = v;
        }
        #pragma unroll
        for (int it = 0; it < 2; ++it) {
            int i = it * 256 + t;
            int kk = i >> 4, q = i & 15;
            *reinterpret_cast<float4*>(&ws[kk][q * 4]) =
                *reinterpret_cast<const float4*>(&W2[(size_t)(k0 + kk) * HDIM + q * 4]);
        }
        __syncthreads();
        #pragma unroll 8
        for (int kk = 0; kk < BK1; ++kk) {
            float4 a = *reinterpret_cast<const float4*>(&xs[kk][tr * 4]);
            float4 w = *reinterpret_cast<const float4*>(&ws[kk][tc * 4]);
            acc[0][0] = fmaf(a.x, w.x, acc[0][0]); acc[0][1] = fmaf(a.x, w.y, acc[0][1]);
            acc[0][2] = fmaf(a.x, w.z, acc[0][2]); acc[0][3] = fmaf(a.x, w.w, acc[0][3]);
            acc[1][0] = fmaf(a.y, w.x, acc[1][0]); acc[1][1] = fmaf(a.y, w.y, acc[1][1]);
            acc[1][2] = fmaf(a.y, w.z, acc[1][2]); acc[1][3] = fmaf(a.y, w.w, acc[1][3]);
            acc[2][0] = fmaf(a.z, w.x, acc[2][0]); acc[2][1] = fmaf(a.z, w.y, acc[2][1]);
            acc[2][2] = fmaf(a.z, w.z, acc[2][2]); acc[2][3] = fmaf(a.z, w.w, acc[2][3]);
            acc[3][0] = fmaf(a.w, w.x, acc[3][0]); acc[3][1] = fmaf(a.w, w.y, acc[3][1]);
            acc[3][2] = fmaf(a.w, w.z, acc[3][2]); acc[3][3] = fmaf(a.w, w.w, acc[3][3]);
        }
    }
    int r = row0 + tr * 4;
    if (r < n) {
        #pragma unroll
        for (int cj = 0; cj < 4; ++cj) {
            int j = tc * 4 + cj;
            float4 v = make_float4(acc[0][cj], acc[1][cj], acc[2][cj], acc[3][cj]);
            *reinterpret_cast<float4*>(&t2t[(size_t)j * n + r]) = v;
        }
    }
}

// per-feature sum & sumsq over transposed activations [64][n]
__global__ __launch_bounds__(256) void k_stats(
        const float* __restrict__ tt, float* __restrict__ sum,
        float* __restrict__ sq, int n) {
    int feat = blockIdx.x >> 3;
    int chunk = blockIdx.x & 7;
    const float4* p = reinterpret_cast<const float4*>(tt + (size_t)feat * n);
    int n4 = n / 4;
    float s = 0.f, q = 0.f;
    for (int i = chunk * 256 + threadIdx.x; i < n4; i += 8 * 256) {
        float4 v = p[i];
        s += v.x + v.y + v.z + v.w;
        q += v.x * v.x + v.y * v.y + v.z * v.z + v.w * v.w;
    }
    if (chunk == 0 && threadIdx.x < (n & 3)) {
        float v = tt[(size_t)feat * n + (n & ~3) + threadIdx.x];
        s += v; q += v * v;
    }
    #pragma unroll
    for (int off = 32; off; off >>= 1) {
        s += __shfl_down(s, off, 64);
        q += __shfl_down(q, off, 64);
    }
    __shared__ float ls[4], lq[4];
    int wid = threadIdx.x >> 6, lane = threadIdx.x & 63;
    if (lane == 0) { ls[wid] = s; lq[wid] = q; }
    __syncthreads();
    if (threadIdx.x == 0) {
        atomicAdd(&sum[feat], ls[0] + ls[1] + ls[2] + ls[3]);
        atomicAdd(&sq[feat],  lq[0] + lq[1] + lq[2] + lq[3]);
    }
}

__global__ void k_finalize(const float* __restrict__ sum, const float* __restrict__ sq,
        const float* __restrict__ g, const float* __restrict__ be,
        float* __restrict__ A, float* __restrict__ B, int n) {
    int j = threadIdx.x;
    if (j >= HDIM) return;
    float mean = sum[j] / (float)n;
    float var = sq[j] / (float)n - mean * mean;
    float istd = 1.0f / sqrtf(var + 1e-5f);
    A[j] = g[j] * istd;
    B[j] = be[j] - mean * istd * g[j];
}

// ---------------- z = relu(bn2(t2)) @ W3 + b3 (GEMV per node) ----------------
__global__ __launch_bounds__(256) void k_zlin(
        const float* __restrict__ t2t, const float* __restrict__ A2,
        const float* __restrict__ B2, const float* __restrict__ W3,
        const float* __restrict__ b3, float* __restrict__ out_z, int n) {
    __shared__ float As[HDIM], Bs[HDIM], Ws[HDIM * DLAT];
    int t = threadIdx.x;
    if (t < HDIM) { As[t] = A2[t]; Bs[t] = B2[t]; }
    for (int i = t; i < HDIM * DLAT; i += 256) Ws[i] = W3[i];
    __syncthreads();
    int row = blockIdx.x * 256 + t;
    if (row >= n) return;
    float z[DLAT];
    #pragma unroll
    for (int j = 0; j < DLAT; ++j) z[j] = b3[j];
    for (int k = 0; k < HDIM; ++k) {
        float hv = fmaxf(fmaf(As[k], t2t[(size_t)k * n + row], Bs[k]), 0.f);
        const float* w = &Ws[k * DLAT];
        #pragma unroll
        for (int j = 0; j < DLAT; ++j) z[j] = fmaf(hv, w[j], z[j]);
    }
    float4* zp = reinterpret_cast<float4*>(&out_z[(size_t)row * DLAT]);
    zp[0] = make_float4(z[0], z[1], z[2], z[3]);
    zp[1] = make_float4(z[4], z[5], z[6], z[7]);
    zp[2] = make_float4(z[8], z[9], z[10], z[11]);
    zp[3] = make_float4(z[12], z[13], z[14], z[15]);
}

// ---------------- radial flow: one thread per (node, class) ----------------
__global__ __launch_bounds__(256) void k_flow(
        const float* __restrict__ zbuf, const float* __restrict__ x0,
        const float* __restrict__ ap, const float* __restrict__ bp,
        const float* __restrict__ mu, const float* __restrict__ lv,
        float* __restrict__ out_logq, float* __restrict__ out_beta, int n) {
    __shared__ float a_s[NL * NC], b_s[NL * NC];
    __shared__ float x0_s[NL * NC][DLAT + 1];
    __shared__ float mu_s[NC][DLAT + 1], iv_s[NC][DLAT + 1], slv_s[NC];
    int t = threadIdx.x;
    for (int i = t; i < NL * NC; i += 256) {
        float a = softplusf(ap[i]);
        a_s[i] = a;
        b_s[i] = softplusf(bp[i]) - a;
    }
    for (int i = t; i < NL * NC * DLAT; i += 256) x0_s[i >> 4][i & 15] = x0[i];
    for (int i = t; i < NC * DLAT; i += 256) {
        mu_s[i >> 4][i & 15] = mu[i];
        iv_s[i >> 4][i & 15] = __expf(-lv[i]);
    }
    if (t < NC) {
        float s = 0.f;
        for (int d = 0; d < DLAT; ++d) s += lv[t * DLAT + d];
        slv_s[t] = s;
    }
    __syncthreads();
    int gid = blockIdx.x * 256 + t;
    int row = gid >> 3, c = gid & 7;
    if (row >= n) return;
    float zz[DLAT];
    const float4* zp = reinterpret_cast<const float4*>(&zbuf[(size_t)row * DLAT]);
    float4 z0 = zp[0], z1 = zp[1], z2 = zp[2], z3 = zp[3];
    zz[0] = z0.x; zz[1] = z0.y; zz[2] = z0.z; zz[3] = z0.w;
    zz[4] = z1.x; zz[5] = z1.y; zz[6] = z1.z; zz[7] = z1.w;
    zz[8] = z2.x; zz[9] = z2.y; zz[10] = z2.z; zz[11] = z2.w;
    zz[12] = z3.x; zz[13] = z3.y; zz[14] = z3.z; zz[15] = z3.w;

    float log_det = 0.f;
    #pragma unroll
    for (int l = NL - 1; l >= 0; --l) {
        int idx = l * NC + c;
        float a = a_s[idx], b = b_s[idx];
        const float* x0p = x0_s[idx];
        float diff[DLAT];
        float r2 = 0.f;
        #pragma unroll
        for (int d = 0; d < DLAT; ++d) {
            diff[d] = zz[d] - x0p[d];
            r2 = fmaf(diff[d], diff[d], r2);
        }
        float r = fmaxf(sqrtf(r2), 1e-8f);
        float h = 1.f / (a + r);
        float bh = b * h;
        #pragma unroll
        for (int d = 0; d < DLAT; ++d) zz[d] = fmaf(bh, diff[d], zz[d]);
        log_det += (DLAT - 1) * __logf(1.f + bh) + __logf(1.f + bh - bh * h * r);
    }
    float quad = 0.f;
    #pragma unroll
    for (int d = 0; d < DLAT; ++d) {
        float dd = zz[d] - mu_s[c][d];
        quad = fmaf(dd * dd, iv_s[c][d], quad);
    }
    float lq = -14.70301653f - 0.5f * slv_s[c] - 0.5f * quad + log_det;
    out_logq[gid] = lq;
    float w = fminf(fmaxf(lq + 20.24819398f, -30.f), 30.f);
    out_beta[gid] = __expf(w);
}

// ---------------- pass 1: radix partition edges into NB row-range buckets ----
__global__ __launch_bounds__(256) void k_bucket(
        const int* __restrict__ rows, const int* __restrict__ cols,
        int2* __restrict__ bpairs, int* __restrict__ bcnt, int cap,
        int* __restrict__ cur, int2* __restrict__ ovf, int* __restrict__ ovf_cnt,
        int e, int n, int rpb) {
    __shared__ int lcnt[NB], loff[NB], lcur[NB], gbase[NB], sc[NB];
    __shared__ int2 staged[TILE];
    int t = threadIdx.x;
    int base = blockIdx.x * TILE;
    for (int i = t; i < NB; i += 256) lcnt[i] = 0;
    __syncthreads();
    int er[PERTHREAD], ec[PERTHREAD], eb[PERTHREAD];
    #pragma unroll
    for (int k = 0; k < PERTHREAD; ++k) {
        int i = base + k * 256 + t;
        eb[k] = -1;
        if (i < e) {
            int r = rows[i], c = cols[i];
            if ((unsigned)r < (unsigned)n && (unsigned)c < (unsigned)n) {
                er[k] = r; ec[k] = c;
                int b = (int)((unsigned)r / (unsigned)rpb);
                eb[k] = b;
                atomicAdd(&lcnt[b], 1);
            }
        }
    }
    __syncthreads();
    if (t < NB) sc[t] = lcnt[t];
    __syncthreads();
    for (int off = 1; off < NB; off <<= 1) {
        int v = 0;
        if (t < NB && t >= off) v = sc[t - off];
        __syncthreads();
        if (t < NB) sc[t] += v;
        __syncthreads();
    }
    if (t < NB) { loff[t] = sc[t] - lcnt[t]; lcur[t] = sc[t] - lcnt[t]; }
    __syncthreads();
    #pragma unroll
    for (int k = 0; k < PERTHREAD; ++k) {
        if (eb[k] >= 0) {
            int slot = atomicAdd(&lcur[eb[k]], 1);
            staged[slot] = make_int2(er[k], ec[k]);
        }
    }
    __syncthreads();
    if (t < NB && lcnt[t] > 0) gbase[t] = atomicAdd(&bcnt[t], lcnt[t]);
    __syncthreads();
    int wid = t >> 6, lane = t & 63;
    for (int b = wid; b < NB; b += 4) {
        int cnt = lcnt[b];
        if (!cnt) continue;
        int gb = gbase[b], lo = loff[b];
        for (int k = lane; k < cnt; k += 64) {
            int2 p = staged[lo + k];
            int dst = gb + k;
            if (dst < cap) {
                bpairs[(size_t)b * cap + dst] = p;
            } else {
                int o = atomicAdd(ovf_cnt, 1);
                if (o < OVF_CAP) ovf[o] = p;
                atomicAdd(&cur[p.x], 1);
            }
        }
    }
}

// ---------------- pass 2: per-bucket ELL placement (L2-local writes) --------
__global__ __launch_bounds__(256) void k_build(
        const int2* __restrict__ bpairs, const int* __restrict__ bcnt, int cap,
        int* __restrict__ ecol, int* __restrict__ cur,
        int2* __restrict__ ovf, int* __restrict__ ovf_cnt, int n, int rpb) {
    __shared__ int lcnt[1024];
    int b = blockIdx.x, t = threadIdx.x;
    int row_base = b * rpb;
    int nrows = n - row_base; if (nrows > rpb) nrows = rpb;
    if (nrows <= 0) return;
    for (int i = t; i < nrows; i += 256) lcnt[i] = 0;
    __syncthreads();
    int m = bcnt[b]; if (m > cap) m = cap;
    const int2* bp = bpairs + (size_t)b * cap;
    for (int i = t; i < m; i += 256) {
        int2 p = bp[i];
        int lr = p.x - row_base;
        int j = atomicAdd(&lcnt[lr], 1);
        if (j < ELLW) {
            ecol[(size_t)p.x * ELLW + j] = p.y;
        } else {
            int o = atomicAdd(ovf_cnt, 1);
            if (o < OVF_CAP) ovf[o] = p;
        }
    }
    __syncthreads();
    for (int i = t; i < nrows; i += 256) {
        int c = lcnt[i];
        if (c) cur[row_base + i] += c;
    }
}

__global__ void k_dis(const int* __restrict__ cur, float* __restrict__ dis, int n) {
    int i = blockIdx.x * blockDim.x + threadIdx.x;
    if (i < n) dis[i] = rsqrtf((float)cur[i] + 1.0f);   // +1 = self loop
}

__global__ void k_init_hs(const float* __restrict__ beta, const float* __restrict__ dis,
                          float* __restrict__ hs, int n) {
    int i = blockIdx.x * blockDim.x + threadIdx.x;
    if (i >= n) return;
    float d = dis[i];
    const float4* b = reinterpret_cast<const float4*>(beta + (size_t)i * NC);
    float4* o = reinterpret_cast<float4*>(hs + (size_t)i * NC);
    float4 b0 = b[0], b1 = b[1];
    o[0] = make_float4(d * b0.x, d * b0.y, d * b0.z, d * b0.w);
    o[1] = make_float4(d * b1.x, d * b1.y, d * b1.z, d * b1.w);
}

// ---------------- APPNP gather iteration ----------------
// 8-wide unrolled edge walk: 8 independent L2 gathers in flight.
__global__ __launch_bounds__(256) void k_gather(
        const int* __restrict__ cur, const int* __restrict__ ecol,
        const float* __restrict__ hs_in, const float* __restrict__ beta,
        const float* __restrict__ dis, float* __restrict__ hout,
        float* __restrict__ hs_out, const int2* __restrict__ ovf,
        const int* __restrict__ ovf_cnt, int n) {
    int row = (blockIdx.x * blockDim.x + threadIdx.x) >> 3;
    int c = threadIdx.x & 7;
    if (row >= n) return;
    int cnt = cur[row];
    int lim = cnt < ELLW ? cnt : ELLW;
    float d = dis[row];
    const int* ec = ecol + (size_t)row * ELLW;
    const int4* ec4 = reinterpret_cast<const int4*>(ec);
    float acc = hs_in[row * NC + c];   // self loop
    float s0 = 0.f, s1 = 0.f, s2 = 0.f, s3 = 0.f;
    float s4 = 0.f, s5 = 0.f, s6 = 0.f, s7 = 0.f;
    int lim8 = lim & ~7;
    for (int ep = 0; ep < lim8; ep += 8) {
        int4 e0 = ec4[(ep >> 2) + 0];
        int4 e1 = ec4[(ep >> 2) + 1];
        s0 += hs_in[e0.x * NC + c];
        s1 += hs_in[e0.y * NC + c];
        s2 += hs_in[e0.z * NC + c];
        s3 += hs_in[e0.w * NC + c];
        s4 += hs_in[e1.x * NC + c];
        s5 += hs_in[e1.y * NC + c];
        s6 += hs_in[e1.z * NC + c];
        s7 += hs_in[e1.w * NC + c];
    }
    for (int ep = lim8; ep < lim; ++ep) acc += hs_in[ec[ep] * NC + c];
    acc += ((s0 + s1) + (s2 + s3)) + ((s4 + s5) + (s6 + s7));
    int m = *ovf_cnt;
    if (m > 0) {   // parachute: expected never taken
        if (m > OVF_CAP) m = OVF_CAP;
        for (int i = 0; i < m; ++i) {
            int2 p = ovf[i];
            if (p.x == row) acc += hs_in[p.y * NC + c];
        }
    }
    float hn = 0.9f * d * acc + 0.1f * beta[row * NC + c];
    hout[row * NC + c] = hn;
    hs_out[row * NC + c] = d * hn;
}

__global__ void k_final(const float* __restrict__ h, float* __restrict__ out_alpha,
        float* __restrict__ out_probs, int n) {
    int i = blockIdx.x * blockDim.x + threadIdx.x;
    if (i >= n) return;
    float a[NC];
    float s = 0.f;
    #pragma unroll
    for (int c = 0; c < NC; ++c) {
        float v = h[(size_t)i * NC + c];
        v = 0.001f + fmaxf(v, 0.f);
        a[c] = v; s += v;
    }
    float inv = 1.f / s;
    #pragma unroll
    for (int c = 0; c < NC; ++c) {
        out_alpha[(size_t)i * NC + c] = a[c];
        out_probs[(size_t)i * NC + c] = a[c] * inv;
    }
}

extern "C" void kernel_launch(void* const* d_in, const int* in_sizes, int n_in,
                              void* d_out, int out_size, void* d_ws, size_t ws_size,
                              hipStream_t stream) {
    const float* x   = (const float*)d_in[0];
    const int*   ei  = (const int*)d_in[1];
    const float* W1  = (const float*)d_in[2];
    const float* b1  = (const float*)d_in[3];
    const float* g1  = (const float*)d_in[4];
    const float* be1 = (const float*)d_in[5];
    const float* W2  = (const float*)d_in[6];
    const float* b2  = (const float*)d_in[7];
    const float* g2  = (const float*)d_in[8];
    const float* be2 = (const float*)d_in[9];
    const float* W3  = (const float*)d_in[10];
    const float* b3  = (const float*)d_in[11];
    const float* x0  = (const float*)d_in[12];
    const float* ap  = (const float*)d_in[13];
    const float* bp  = (const float*)d_in[14];
    const float* mu  = (const float*)d_in[15];
    const float* lv  = (const float*)d_in[16];

    int n = in_sizes[0] / NFEAT_IN;   // 100000
    int e = in_sizes[1] / 2;          // 3200000
    const int* rows = ei;
    const int* cols = ei + e;
    int rpb = (n + NB - 1) / NB;      // 782 rows per bucket
    int cap = (e + e / 16) / NB;      // pairs/bucket (+~10 sigma slack)

    size_t an = (size_t)HDIM * n;
    float* ws  = (float*)d_ws;
    float* t1t = ws;                         // 64n floats; later ecol (64n ints)
    float* t2t = ws + an;                    // 64n floats; later bucket pairs
    int2*  bpairs = (int2*)t2t;              // NB*cap int2
    float* stats = (float*)((char*)t2t + (size_t)NB * cap * sizeof(int2));
    float *sum1 = stats,       *sq1 = stats + 64,  *A1 = stats + 128, *B1 = stats + 192;
    float *sum2 = stats + 256, *sq2 = stats + 320, *A2 = stats + 384, *B2 = stats + 448;
    int*  bcnt    = (int*)(stats + 512);     // NB
    int*  ovf_cnt = bcnt + NB;               // 1 (+pad)
    int2* ovf     = (int2*)(ovf_cnt + 4);    // OVF_CAP int2
    float* hs0 = (float*)bpairs;             // overlays dead bucket region
    float* hs1 = hs0 + (size_t)NC * n;
    int* ecol = (int*)t1t;

    float* out = (float*)d_out;
    float* out_alpha = out;                  // doubles as hout during APPNP
    float* out_probs = out + (size_t)n * NC; // holds cur/dis until k_final
    float* out_z     = out + (size_t)2 * n * NC;
    float* out_beta  = out_z + (size_t)n * DLAT;
    float* out_logq  = out_beta + (size_t)n * NC;

    int*   cur = (int*)out_probs;            // n ints
    float* dis = out_probs + n;              // n floats

    int nb_nodes = (n + 255) / 256;
    int nb_gemm  = (n + BM - 1) / BM;
    int nb_nc    = (int)(((size_t)n * NC + 255) / 256);

    hipMemsetAsync(stats, 0, (512 + NB + 4) * sizeof(float), stream);

    // encoder
    k_gemm1<<<nb_gemm, 256, 0, stream>>>(x, W1, b1, t1t, n);
    k_stats<<<HDIM * 8, 256, 0, stream>>>(t1t, sum1, sq1, n);
    k_finalize<<<1, 64, 0, stream>>>(sum1, sq1, g1, be1, A1, B1, n);
    k_gemm2<<<nb_gemm, 256, 0, stream>>>(t1t, A1, B1, W2, b2, t2t, n);
    k_stats<<<HDIM * 8, 256, 0, stream>>>(t2t, sum2, sq2, n);
    k_finalize<<<1, 64, 0, stream>>>(sum2, sq2, g2, be2, A2, B2, n);
    k_zlin<<<nb_nodes, 256, 0, stream>>>(t2t, A2, B2, W3, b3, out_z, n);
    k_flow<<<nb_nc, 256, 0, stream>>>(out_z, x0, ap, bp, mu, lv,
                                      out_logq, out_beta, n);

    // graph build: radix partition then per-bucket ELL placement
    hipMemsetAsync(cur, 0, (size_t)n * sizeof(int), stream);
    int nt_bucket = (e + TILE - 1) / TILE;
    k_bucket<<<nt_bucket, 256, 0, stream>>>(rows, cols, bpairs, bcnt, cap,
                                            cur, ovf, ovf_cnt, e, n, rpb);
    k_build<<<NB, 256, 0, stream>>>(bpairs, bcnt, cap, ecol, cur, ovf, ovf_cnt, n, rpb);
    k_dis<<<nb_nodes, 256, 0, stream>>>(cur, dis, n);
    k_init_hs<<<nb_nodes, 256, 0, stream>>>(out_beta, dis, hs0, n);

    // APPNP: 10 gather rounds, ping-pong hs0/hs1; hout lives in out_alpha
    for (int it = 0; it < KPROP; ++it) {
        const float* hin = (it & 1) ? hs1 : hs0;
        float* hso = (it & 1) ? hs0 : hs1;
        k_gather<<<nb_nc, 256, 0, stream>>>(cur, ecol, hin, out_beta, dis,
                                            out_alpha, hso, ovf, ovf_cnt, n);
    }
    k_final<<<nb_nodes, 256, 0, stream>>>(out_alpha, out_alpha, out_probs, n);
}